// Round 1
// baseline (554.896 us; speedup 1.0000x reference)
//
#include <hip/hip_runtime.h>

#define BB 128
#define TT 224
#define LL 224

__device__ __forceinline__ float sigmf(float x){ return 1.0f/(1.0f + __expf(-x)); }
__device__ __forceinline__ float tanhfast(float x){ return 1.0f - 2.0f/(__expf(2.0f*x)+1.0f); }

// ---------------- K1: conv chain (both branches) ----------------
// one thread per final output element (branch, row=b*T+t, j<28)
__global__ void conv_chain_kernel(const float* __restrict__ x,
    const float* __restrict__ c1w1, const float* __restrict__ c1b1,
    const float* __restrict__ c1w2, const float* __restrict__ c1b2,
    const float* __restrict__ c2w1, const float* __restrict__ c2b1,
    const float* __restrict__ c2w2, const float* __restrict__ c2b2,
    float* __restrict__ y)
{
  int idx = blockIdx.x*256 + threadIdx.x;
  if (idx >= 2*BB*TT*28) return;
  int branch = idx / (BB*TT*28);
  int rem = idx - branch*(BB*TT*28);
  int row = rem / 28;
  int j   = rem - row*28;
  const float* w1 = branch ? c2w1 : c1w1;
  const float* w2 = branch ? c2w2 : c1w2;
  float b1  = branch ? c2b1[0] : c1b1[0];
  float b2v = branch ? c2b2[0] : c1b2[0];
  const float* xrow = x + (size_t)branch*BB*TT*LL + (size_t)row*LL;
  float w1r[8];
  #pragma unroll
  for (int k=0;k<8;k++) w1r[k]=w1[k];

  // conv1 (stride4 pad2) + relu, local conv indices cj = 2j-3 .. 2j+4
  float cv[8];
  #pragma unroll
  for (int q=0;q<8;q++){
    int cj = 2*j-3+q;
    float s;
    if (cj>=0 && cj<56){
      s = b1;
      int base = 4*cj-2;
      #pragma unroll
      for (int k=0;k<8;k++){
        int xi = base+k;
        float xv = (xi>=0 && xi<LL) ? xrow[xi] : 0.0f;
        s += xv * w1r[k];
      }
      s = fmaxf(s, 0.0f);
    } else {
      s = -1e30f;   // -inf padding for reduce_window
    }
    cv[q]=s;
  }
  // maxpool window4 stride2 pad1 (+relu no-op), then conv3 pad1 + relu
  float outv = b2v;
  #pragma unroll
  for (int pi=0;pi<3;pi++){
    int p = j-1+pi;
    float pool = 0.0f;               // conv2 zero padding outside [0,28)
    if (p>=0 && p<28){
      pool = fmaxf(fmaxf(cv[2*pi],cv[2*pi+1]), fmaxf(cv[2*pi+2],cv[2*pi+3]));
      pool = fmaxf(pool, 0.0f);
    }
    outv += pool * w2[pi];
  }
  outv = fmaxf(outv,0.0f);
  y[(size_t)branch*BB*TT*28 + (size_t)row*28 + j] = outv;
}

// ---------------- K2: pre-gate GEMM  pre[r][t][b][k*4+g] = bias + x@Wih^T --
// grid = 4 runs * 1344 blocks of 256; lin = (t*128+b)*12 + k
__global__ void pregate_kernel(const float* __restrict__ in, int inStrideBranch, int D,
    const float* __restrict__ wihA, const float* __restrict__ biasA,
    const float* __restrict__ wihB, const float* __restrict__ biasB,
    float* __restrict__ pre)
{
  int r = blockIdx.x / 1344;
  int lin = (blockIdx.x % 1344)*256 + threadIdx.x;
  int br = r>>1, dir = r&1;
  const float* wih  = (br ? wihB  : wihA)  + dir*48*D;
  const float* bias = (br ? biasB : biasA) + dir*48;
  __shared__ float wL[48*28];
  __shared__ float bL[48];
  for (int i = threadIdx.x; i < 48*D; i += 256) wL[i]=wih[i];
  if (threadIdx.x < 48) bL[threadIdx.x]=bias[threadIdx.x];
  __syncthreads();
  int tb = lin/12;  int k = lin - tb*12;
  int t  = tb >> 7; int b = tb & 127;
  const float* rowp = in + (size_t)br*inStrideBranch + ((size_t)b*TT + t)*D;
  float aI=bL[k], aF=bL[12+k], aG=bL[24+k], aO=bL[36+k];
  for (int d=0; d<D; d++){
    float xv = rowp[d];
    aI += xv * wL[(0*12+k)*D + d];
    aF += xv * wL[(1*12+k)*D + d];
    aG += xv * wL[(2*12+k)*D + d];
    aO += xv * wL[(3*12+k)*D + d];
  }
  float4* o = (float4*)(pre + (size_t)r*(TT*BB*48) + (size_t)tb*48 + k*4);
  *o = make_float4(aI,aF,aG,aO);
}

// ---------------- K3: recurrent LSTM scan (4 runs, 1-wave blocks) --------
// block = 64 threads = 4 batch x 16 lanes (12 active: hidden unit k)
__global__ __launch_bounds__(64) void lstm_kernel(const float* __restrict__ pre,
    const float* __restrict__ whhA, const float* __restrict__ whhB,
    float* __restrict__ out)
{
  int blk = blockIdx.x;
  int r   = blk >> 5;            // run 0..3
  int br  = r >> 1, dir = r & 1;
  int lane = threadIdx.x;
  int sub  = lane >> 4;
  int k    = lane & 15;
  int keff = (k < 12) ? k : 11;
  int b    = (blk & 31)*4 + sub;
  const float* preR = pre + (size_t)r*(TT*BB*48) + (size_t)b*48 + keff*4;
  const float* whh  = (br ? whhB : whhA) + dir*48*12;
  float* outR = out + (size_t)br*(BB*TT*24) + (size_t)b*TT*24 + dir*12 + keff;

  float wi[12], wf[12], wg[12], wo[12];
  #pragma unroll
  for (int j=0;j<12;j++){
    wi[j]=whh[(    keff)*12+j];
    wf[j]=whh[(12+keff)*12+j];
    wg[j]=whh[(24+keff)*12+j];
    wo[j]=whh[(36+keff)*12+j];
  }

  __shared__ float hb[2][4][16];
  hb[0][sub][k]=0.f;
  float c = 0.f;
  const int tstep = dir ? -1 : 1;
  int t = dir ? (TT-1) : 0;

  for (int s=0;s<TT;s++){
    const float4 p4 = *(const float4*)(preR + (size_t)t*(128*48));
    float4 h0 = *(const float4*)&hb[s&1][sub][0];
    float4 h1 = *(const float4*)&hb[s&1][sub][4];
    float4 h2 = *(const float4*)&hb[s&1][sub][8];
    float h[12];
    *(float4*)&h[0]=h0; *(float4*)&h[4]=h1; *(float4*)&h[8]=h2;
    float gi=p4.x, gf=p4.y, gg=p4.z, go=p4.w;
    #pragma unroll
    for (int j=0;j<12;j++){
      gi += wi[j]*h[j];
      gf += wf[j]*h[j];
      gg += wg[j]*h[j];
      go += wo[j]*h[j];
    }
    float si=sigmf(gi), sf=sigmf(gf), tg=tanhfast(gg), so=sigmf(go);
    c = sf*c + si*tg;
    float hv = so * tanhfast(c);
    if (k < 12){
      hb[(s+1)&1][sub][k]=hv;
      outR[(size_t)t*24] = hv;
    }
    t += tstep;
  }
}

// ---------------- K6a: Wt = W3(9,192) @ W2(192,1024) ----------------------
__global__ void wcomp1_kernel(const float* __restrict__ fcw3, const float* __restrict__ fcw2,
                              float* __restrict__ Wt)
{
  int idx = blockIdx.x*256+threadIdx.x;
  if (idx >= 9*1024) return;
  int o = idx >> 10;
  int n = idx & 1023;
  float acc = 0.f;
  for (int p=0;p<192;p++) acc += fcw3[o*192+p]*fcw2[p*1024+n];
  Wt[idx] = acc;
}

// ---------------- K6b: Wc = Wt(9,1024) @ W1(1024,5376); BC composite bias --
__global__ void wcomp2_kernel(const float* __restrict__ Wt, const float* __restrict__ fcw1,
    const float* __restrict__ fcb1, const float* __restrict__ fcb2,
    const float* __restrict__ fcw3, const float* __restrict__ fcb3,
    float* __restrict__ Wc, float* __restrict__ BC)
{
  __shared__ float wtL[9*1024];
  for (int i=threadIdx.x;i<9*1024;i+=256) wtL[i]=Wt[i];
  __syncthreads();
  int j = blockIdx.x*256 + threadIdx.x;   // < 5376 (21 blocks)
  float acc[9];
  #pragma unroll
  for (int o=0;o<9;o++) acc[o]=0.f;
  for (int n=0;n<1024;n++){
    float v = fcw1[(size_t)n*5376 + j];
    #pragma unroll
    for (int o=0;o<9;o++) acc[o] += wtL[o*1024+n]*v;
  }
  #pragma unroll
  for (int o=0;o<9;o++) Wc[(size_t)o*5376 + j] = acc[o];
  if (blockIdx.x==0 && threadIdx.x<9){
    int o = threadIdx.x;
    float bc = fcb3[o];
    for (int p=0;p<192;p++)  bc += fcw3[o*192+p]*fcb2[p];
    for (int n=0;n<1024;n++) bc += wtL[o*1024+n]*fcb1[n];
    BC[o]=bc;
  }
}

// ---------------- K6c: out[m][o] = (w1*o1+w2*o2) . Wc[o] + BC[o] ----------
__global__ void final_kernel(const float* __restrict__ o1, const float* __restrict__ o2,
    const float* __restrict__ Wc, const float* __restrict__ BC,
    const float* __restrict__ w1p, const float* __restrict__ w2p,
    float* __restrict__ out)
{
  int wid  = blockIdx.x*4 + (threadIdx.x>>6);
  int lane = threadIdx.x & 63;
  if (wid >= 128*9) return;
  int m = wid / 9, o = wid - m*9;
  float w1 = w1p[0], w2 = w2p[0];
  const float* r1 = o1 + (size_t)m*5376;
  const float* r2 = o2 + (size_t)m*5376;
  const float* wc = Wc + (size_t)o*5376;
  float acc = 0.f;
  for (int i=lane;i<5376;i+=64){
    acc += (w1*r1[i] + w2*r2[i]) * wc[i];
  }
  #pragma unroll
  for (int off=32;off;off>>=1) acc += __shfl_down(acc, off);
  if (lane==0) out[m*9+o] = acc + BC[o];
}

extern "C" void kernel_launch(void* const* d_in, const int* in_sizes, int n_in,
                              void* d_out, int out_size, void* d_ws, size_t ws_size,
                              hipStream_t stream) {
  (void)in_sizes; (void)n_in; (void)out_size; (void)ws_size;
  const float* x    = (const float*)d_in[0];
  const float* c1w1 = (const float*)d_in[1];
  const float* c1b1 = (const float*)d_in[2];
  const float* c1w2 = (const float*)d_in[3];
  const float* c1b2 = (const float*)d_in[4];
  const float* c2w1 = (const float*)d_in[5];
  const float* c2b1 = (const float*)d_in[6];
  const float* c2w2 = (const float*)d_in[7];
  const float* c2b2 = (const float*)d_in[8];
  const float* l10Wih = (const float*)d_in[9];
  const float* l10Whh = (const float*)d_in[10];
  const float* l10b   = (const float*)d_in[11];
  const float* l11Wih = (const float*)d_in[12];
  const float* l11Whh = (const float*)d_in[13];
  const float* l11b   = (const float*)d_in[14];
  const float* l20Wih = (const float*)d_in[15];
  const float* l20Whh = (const float*)d_in[16];
  const float* l20b   = (const float*)d_in[17];
  const float* l21Wih = (const float*)d_in[18];
  const float* l21Whh = (const float*)d_in[19];
  const float* l21b   = (const float*)d_in[20];
  const float* fcw1 = (const float*)d_in[21];
  const float* fcb1 = (const float*)d_in[22];
  const float* fcw2 = (const float*)d_in[23];
  const float* fcb2 = (const float*)d_in[24];
  const float* fcw3 = (const float*)d_in[25];
  const float* fcb3 = (const float*)d_in[26];
  const float* w1   = (const float*)d_in[27];
  const float* w2   = (const float*)d_in[28];
  float* out = (float*)d_out;

  float* ws  = (float*)d_ws;
  float* y    = ws;                       // 2 * 802816
  float* pre  = y   + 2*802816;           // 4 * 1376256
  float* ol0  = pre + 4*1376256;          // 2 * 688128
  float* ol1  = ol0 + 2*688128;           // 2 * 688128
  float* Wt   = ol1 + 2*688128;           // 9216
  float* Wc   = Wt  + 9216;               // 48384
  float* BC   = Wc  + 48384;              // 9

  conv_chain_kernel<<<6272,256,0,stream>>>(x, c1w1,c1b1,c1w2,c1b2, c2w1,c2b1,c2w2,c2b2, y);
  pregate_kernel<<<4*1344,256,0,stream>>>(y,   802816, 28, l10Wih, l10b, l20Wih, l20b, pre);
  lstm_kernel<<<128,64,0,stream>>>(pre, l10Whh, l20Whh, ol0);
  pregate_kernel<<<4*1344,256,0,stream>>>(ol0, 688128, 24, l11Wih, l11b, l21Wih, l21b, pre);
  lstm_kernel<<<128,64,0,stream>>>(pre, l11Whh, l21Whh, ol1);
  wcomp1_kernel<<<36,256,0,stream>>>(fcw3, fcw2, Wt);
  wcomp2_kernel<<<21,256,0,stream>>>(Wt, fcw1, fcb1, fcb2, fcw3, fcb3, Wc, BC);
  final_kernel<<<288,256,0,stream>>>(ol1, ol1+688128, Wc, BC, w1, w2, out);
}

// Round 2
// 438.607 us; speedup vs baseline: 1.2651x; 1.2651x over previous
//
#include <hip/hip_runtime.h>

#define BB 128
#define TT 224
#define LL 224

__device__ __forceinline__ float sigmf(float x){ return 1.0f/(1.0f + __expf(-x)); }
__device__ __forceinline__ float tanhfast(float x){ return 1.0f - 2.0f/(__expf(2.0f*x)+1.0f); }

// ---------------- K1: conv chain (both branches) ----------------
__global__ void conv_chain_kernel(const float* __restrict__ x,
    const float* __restrict__ c1w1, const float* __restrict__ c1b1,
    const float* __restrict__ c1w2, const float* __restrict__ c1b2,
    const float* __restrict__ c2w1, const float* __restrict__ c2b1,
    const float* __restrict__ c2w2, const float* __restrict__ c2b2,
    float* __restrict__ y)
{
  int idx = blockIdx.x*256 + threadIdx.x;
  if (idx >= 2*BB*TT*28) return;
  int branch = idx / (BB*TT*28);
  int rem = idx - branch*(BB*TT*28);
  int row = rem / 28;
  int j   = rem - row*28;
  const float* w1 = branch ? c2w1 : c1w1;
  const float* w2 = branch ? c2w2 : c1w2;
  float b1  = branch ? c2b1[0] : c1b1[0];
  float b2v = branch ? c2b2[0] : c1b2[0];
  const float* xrow = x + (size_t)branch*BB*TT*LL + (size_t)row*LL;
  float w1r[8];
  #pragma unroll
  for (int k=0;k<8;k++) w1r[k]=w1[k];

  float cv[8];
  #pragma unroll
  for (int q=0;q<8;q++){
    int cj = 2*j-3+q;
    float s;
    if (cj>=0 && cj<56){
      s = b1;
      int base = 4*cj-2;
      #pragma unroll
      for (int k=0;k<8;k++){
        int xi = base+k;
        float xv = (xi>=0 && xi<LL) ? xrow[xi] : 0.0f;
        s += xv * w1r[k];
      }
      s = fmaxf(s, 0.0f);
    } else {
      s = -1e30f;
    }
    cv[q]=s;
  }
  float outv = b2v;
  #pragma unroll
  for (int pi=0;pi<3;pi++){
    int p = j-1+pi;
    float pool = 0.0f;
    if (p>=0 && p<28){
      pool = fmaxf(fmaxf(cv[2*pi],cv[2*pi+1]), fmaxf(cv[2*pi+2],cv[2*pi+3]));
      pool = fmaxf(pool, 0.0f);
    }
    outv += pool * w2[pi];
  }
  outv = fmaxf(outv,0.0f);
  y[(size_t)branch*BB*TT*28 + (size_t)row*28 + j] = outv;
}

// ---------------- K2: pre-gate GEMM ----------------
__global__ void pregate_kernel(const float* __restrict__ in, int inStrideBranch, int D,
    const float* __restrict__ wihA, const float* __restrict__ biasA,
    const float* __restrict__ wihB, const float* __restrict__ biasB,
    float* __restrict__ pre)
{
  int r = blockIdx.x / 1344;
  int lin = (blockIdx.x % 1344)*256 + threadIdx.x;
  int br = r>>1, dir = r&1;
  const float* wih  = (br ? wihB  : wihA)  + dir*48*D;
  const float* bias = (br ? biasB : biasA) + dir*48;
  __shared__ float wL[48*28];
  __shared__ float bL[48];
  for (int i = threadIdx.x; i < 48*D; i += 256) wL[i]=wih[i];
  if (threadIdx.x < 48) bL[threadIdx.x]=bias[threadIdx.x];
  __syncthreads();
  int tb = lin/12;  int k = lin - tb*12;
  int t  = tb >> 7; int b = tb & 127;
  const float* rowp = in + (size_t)br*inStrideBranch + ((size_t)b*TT + t)*D;
  float aI=bL[k], aF=bL[12+k], aG=bL[24+k], aO=bL[36+k];
  for (int d=0; d<D; d++){
    float xv = rowp[d];
    aI += xv * wL[(0*12+k)*D + d];
    aF += xv * wL[(1*12+k)*D + d];
    aG += xv * wL[(2*12+k)*D + d];
    aO += xv * wL[(3*12+k)*D + d];
  }
  float4* o = (float4*)(pre + (size_t)r*(TT*BB*48) + (size_t)tb*48 + k*4);
  *o = make_float4(aI,aF,aG,aO);
}

// ---------------- K3: recurrent LSTM scan (shfl h-exchange + prefetch) ----
__global__ __launch_bounds__(64) void lstm_kernel(const float* __restrict__ pre,
    const float* __restrict__ whhA, const float* __restrict__ whhB,
    float* __restrict__ out)
{
  int blk = blockIdx.x;
  int r   = blk >> 5;            // run 0..3
  int br  = r >> 1, dir = r & 1;
  int lane = threadIdx.x;
  int sub  = lane >> 4;
  int k    = lane & 15;
  int keff = (k < 12) ? k : 11;
  int b    = (blk & 31)*4 + sub;
  const float* preR = pre + (size_t)r*(TT*BB*48) + (size_t)b*48 + keff*4;
  const float* whh  = (br ? whhB : whhA) + dir*48*12;
  float* outR = out + (size_t)br*(BB*TT*24) + (size_t)b*TT*24 + dir*12 + keff;

  float wi[12], wf[12], wg[12], wo[12];
  #pragma unroll
  for (int j=0;j<12;j++){
    wi[j]=whh[(    keff)*12+j];
    wf[j]=whh[(12+keff)*12+j];
    wg[j]=whh[(24+keff)*12+j];
    wo[j]=whh[(36+keff)*12+j];
  }

  float c = 0.f, hv = 0.f;
  const int ts = dir ? -1 : 1;
  int t = dir ? (TT-1) : 0;
  const int base = sub << 4;

  float4 pa = *(const float4*)(preR + (size_t)t*6144);
  float4 pb = *(const float4*)(preR + (size_t)(t+ts)*6144);

  for (int s=0;s<TT;s++){
    int tp = t + 2*ts;
    tp = tp < 0 ? 0 : (tp > TT-1 ? TT-1 : tp);
    float4 pc = *(const float4*)(preR + (size_t)tp*6144);

    float h[12];
    #pragma unroll
    for (int j=0;j<12;j++) h[j] = __shfl(hv, base + j, 64);

    float gi=pa.x, gf=pa.y, gg=pa.z, go=pa.w;
    #pragma unroll
    for (int j=0;j<12;j++){
      gi += wi[j]*h[j];
      gf += wf[j]*h[j];
      gg += wg[j]*h[j];
      go += wo[j]*h[j];
    }
    float si=sigmf(gi), sf=sigmf(gf), tg=tanhfast(gg), so=sigmf(go);
    c = sf*c + si*tg;
    hv = so * tanhfast(c);
    if (k < 12) outR[(size_t)t*24] = hv;
    pa = pb; pb = pc;
    t += ts;
  }
}

// ---------------- K6a: Wt = W3(9,192) @ W2(192,1024) ----------------------
__global__ void wcomp1_kernel(const float* __restrict__ fcw3, const float* __restrict__ fcw2,
                              float* __restrict__ Wt)
{
  int idx = blockIdx.x*256+threadIdx.x;
  if (idx >= 9*1024) return;
  int o = idx >> 10;
  int n = idx & 1023;
  float acc = 0.f;
  for (int p=0;p<192;p++) acc += fcw3[o*192+p]*fcw2[p*1024+n];
  Wt[idx] = acc;
}

// ---------------- K6b-A: split-K partials  wpart[s][o][j] ------------------
// grid = 16 s-chunks * 21 j-blocks, 256 thr
__global__ void wpartA_kernel(const float* __restrict__ Wt, const float* __restrict__ fcw1,
                              float* __restrict__ wpart)
{
  int s  = blockIdx.x / 21;
  int jb = blockIdx.x % 21;
  int j  = jb*256 + threadIdx.x;      // < 5376
  __shared__ float wtL[9*64];
  for (int i=threadIdx.x;i<9*64;i+=256){
    int o=i>>6, n=i&63;
    wtL[i]=Wt[o*1024 + s*64 + n];
  }
  __syncthreads();
  float acc[9];
  #pragma unroll
  for (int o=0;o<9;o++) acc[o]=0.f;
  int nbase = s*64;
  for (int n=0;n<64;n++){
    float v = fcw1[(size_t)(nbase+n)*5376 + j];
    #pragma unroll
    for (int o=0;o<9;o++) acc[o] += wtL[o*64+n]*v;
  }
  #pragma unroll
  for (int o=0;o<9;o++) wpart[((size_t)s*9+o)*5376 + j] = acc[o];
}

// ---------------- K6b-B: Wc = sum_s wpart[s] ------------------------------
__global__ void wpartB_kernel(const float* __restrict__ wpart, float* __restrict__ Wc)
{
  int idx = blockIdx.x*256+threadIdx.x;     // 189 blocks = 48384
  if (idx >= 48384) return;
  float a = 0.f;
  #pragma unroll
  for (int s=0;s<16;s++) a += wpart[(size_t)s*48384 + idx];
  Wc[idx] = a;
}

// ---------------- K6b-C: composite bias BC (9 blocks, wave-reduce) --------
__global__ void bcomp_kernel(const float* __restrict__ Wt,
    const float* __restrict__ fcb1, const float* __restrict__ fcb2,
    const float* __restrict__ fcw3, const float* __restrict__ fcb3,
    float* __restrict__ BC)
{
  int o = blockIdx.x;           // 9 blocks, 64 threads
  int lane = threadIdx.x;
  float acc = 0.f;
  for (int p=lane;p<192;p+=64)  acc += fcw3[o*192+p]*fcb2[p];
  for (int n=lane;n<1024;n+=64) acc += Wt[o*1024+n]*fcb1[n];
  #pragma unroll
  for (int off=32;off;off>>=1) acc += __shfl_down(acc, off);
  if (lane==0) BC[o] = acc + fcb3[o];
}

// ---------------- K6c: out[m][o] = (w1*o1+w2*o2) . Wc[o] + BC[o] ----------
__global__ void final_kernel(const float* __restrict__ o1, const float* __restrict__ o2,
    const float* __restrict__ Wc, const float* __restrict__ BC,
    const float* __restrict__ w1p, const float* __restrict__ w2p,
    float* __restrict__ out)
{
  int wid  = blockIdx.x*4 + (threadIdx.x>>6);
  int lane = threadIdx.x & 63;
  if (wid >= 128*9) return;
  int m = wid / 9, o = wid - m*9;
  float w1 = w1p[0], w2 = w2p[0];
  const float* r1 = o1 + (size_t)m*5376;
  const float* r2 = o2 + (size_t)m*5376;
  const float* wc = Wc + (size_t)o*5376;
  float acc = 0.f;
  for (int i=lane;i<5376;i+=64){
    acc += (w1*r1[i] + w2*r2[i]) * wc[i];
  }
  #pragma unroll
  for (int off=32;off;off>>=1) acc += __shfl_down(acc, off);
  if (lane==0) out[m*9+o] = acc + BC[o];
}

extern "C" void kernel_launch(void* const* d_in, const int* in_sizes, int n_in,
                              void* d_out, int out_size, void* d_ws, size_t ws_size,
                              hipStream_t stream) {
  (void)in_sizes; (void)n_in; (void)out_size; (void)ws_size;
  const float* x    = (const float*)d_in[0];
  const float* c1w1 = (const float*)d_in[1];
  const float* c1b1 = (const float*)d_in[2];
  const float* c1w2 = (const float*)d_in[3];
  const float* c1b2 = (const float*)d_in[4];
  const float* c2w1 = (const float*)d_in[5];
  const float* c2b1 = (const float*)d_in[6];
  const float* c2w2 = (const float*)d_in[7];
  const float* c2b2 = (const float*)d_in[8];
  const float* l10Wih = (const float*)d_in[9];
  const float* l10Whh = (const float*)d_in[10];
  const float* l10b   = (const float*)d_in[11];
  const float* l11Wih = (const float*)d_in[12];
  const float* l11Whh = (const float*)d_in[13];
  const float* l11b   = (const float*)d_in[14];
  const float* l20Wih = (const float*)d_in[15];
  const float* l20Whh = (const float*)d_in[16];
  const float* l20b   = (const float*)d_in[17];
  const float* l21Wih = (const float*)d_in[18];
  const float* l21Whh = (const float*)d_in[19];
  const float* l21b   = (const float*)d_in[20];
  const float* fcw1 = (const float*)d_in[21];
  const float* fcb1 = (const float*)d_in[22];
  const float* fcw2 = (const float*)d_in[23];
  const float* fcb2 = (const float*)d_in[24];
  const float* fcw3 = (const float*)d_in[25];
  const float* fcb3 = (const float*)d_in[26];
  const float* w1   = (const float*)d_in[27];
  const float* w2   = (const float*)d_in[28];
  float* out = (float*)d_out;

  float* ws  = (float*)d_ws;
  float* y    = ws;                       // 2 * 802816  (dead after pregate #1)
  float* pre  = y   + 2*802816;           // 4 * 1376256
  float* ol0  = pre + 4*1376256;          // 2 * 688128
  float* ol1  = ol0 + 2*688128;           // 2 * 688128
  float* Wt   = ol1 + 2*688128;           // 9216
  float* Wc   = Wt  + 9216;               // 48384
  float* BC   = Wc  + 48384;              // 9
  float* wpart = y;                       // alias: 16*9*5376 = 774144 < 1605632

  conv_chain_kernel<<<6272,256,0,stream>>>(x, c1w1,c1b1,c1w2,c1b2, c2w1,c2b1,c2w2,c2b2, y);
  pregate_kernel<<<4*1344,256,0,stream>>>(y,   802816, 28, l10Wih, l10b, l20Wih, l20b, pre);
  lstm_kernel<<<128,64,0,stream>>>(pre, l10Whh, l20Whh, ol0);
  pregate_kernel<<<4*1344,256,0,stream>>>(ol0, 688128, 24, l11Wih, l11b, l21Wih, l21b, pre);
  lstm_kernel<<<128,64,0,stream>>>(pre, l11Whh, l21Whh, ol1);
  wcomp1_kernel<<<36,256,0,stream>>>(fcw3, fcw2, Wt);
  wpartA_kernel<<<336,256,0,stream>>>(Wt, fcw1, wpart);
  wpartB_kernel<<<189,256,0,stream>>>(wpart, Wc);
  bcomp_kernel<<<9,64,0,stream>>>(Wt, fcb1, fcb2, fcw3, fcb3, BC);
  final_kernel<<<288,256,0,stream>>>(ol1, ol1+688128, Wc, BC, w1, w2, out);
}

// Round 3
// 334.695 us; speedup vs baseline: 1.6579x; 1.3105x over previous
//
#include <hip/hip_runtime.h>

#define BB 128
#define TT 224
#define LL 224

typedef float v2f __attribute__((ext_vector_type(2)));

__device__ __forceinline__ float sigmf(float x){ return 1.0f/(1.0f + __expf(-x)); }
__device__ __forceinline__ float tanhfast(float x){ return 1.0f - 2.0f/(__expf(2.0f*x)+1.0f); }

// ---------------- K1: conv chain (both branches) ----------------
__global__ void conv_chain_kernel(const float* __restrict__ x,
    const float* __restrict__ c1w1, const float* __restrict__ c1b1,
    const float* __restrict__ c1w2, const float* __restrict__ c1b2,
    const float* __restrict__ c2w1, const float* __restrict__ c2b1,
    const float* __restrict__ c2w2, const float* __restrict__ c2b2,
    float* __restrict__ y)
{
  int idx = blockIdx.x*256 + threadIdx.x;
  if (idx >= 2*BB*TT*28) return;
  int branch = idx / (BB*TT*28);
  int rem = idx - branch*(BB*TT*28);
  int row = rem / 28;
  int j   = rem - row*28;
  const float* w1 = branch ? c2w1 : c1w1;
  const float* w2 = branch ? c2w2 : c1w2;
  float b1  = branch ? c2b1[0] : c1b1[0];
  float b2v = branch ? c2b2[0] : c1b2[0];
  const float* xrow = x + (size_t)branch*BB*TT*LL + (size_t)row*LL;
  float w1r[8];
  #pragma unroll
  for (int k=0;k<8;k++) w1r[k]=w1[k];

  float cv[8];
  #pragma unroll
  for (int q=0;q<8;q++){
    int cj = 2*j-3+q;
    float s;
    if (cj>=0 && cj<56){
      s = b1;
      int base = 4*cj-2;
      #pragma unroll
      for (int k=0;k<8;k++){
        int xi = base+k;
        float xv = (xi>=0 && xi<LL) ? xrow[xi] : 0.0f;
        s += xv * w1r[k];
      }
      s = fmaxf(s, 0.0f);
    } else {
      s = -1e30f;
    }
    cv[q]=s;
  }
  float outv = b2v;
  #pragma unroll
  for (int pi=0;pi<3;pi++){
    int p = j-1+pi;
    float pool = 0.0f;
    if (p>=0 && p<28){
      pool = fmaxf(fmaxf(cv[2*pi],cv[2*pi+1]), fmaxf(cv[2*pi+2],cv[2*pi+3]));
      pool = fmaxf(pool, 0.0f);
    }
    outv += pool * w2[pi];
  }
  outv = fmaxf(outv,0.0f);
  y[(size_t)branch*BB*TT*28 + (size_t)row*28 + j] = outv;
}

// ---------------- K2: pre-gate GEMM (float4-vectorized) ----------------
__global__ void pregate_kernel(const float* __restrict__ in, int inStrideBranch, int D,
    const float* __restrict__ wihA, const float* __restrict__ biasA,
    const float* __restrict__ wihB, const float* __restrict__ biasB,
    float* __restrict__ pre)
{
  int r = blockIdx.x / 1344;
  int lin = (blockIdx.x % 1344)*256 + threadIdx.x;
  int br = r>>1, dir = r&1;
  const float* wih  = (br ? wihB  : wihA)  + dir*48*D;
  const float* bias = (br ? biasB : biasA) + dir*48;
  __shared__ float wL[48*28];
  __shared__ float bL[48];
  for (int i = threadIdx.x; i < 48*D; i += 256) wL[i]=wih[i];
  if (threadIdx.x < 48) bL[threadIdx.x]=bias[threadIdx.x];
  __syncthreads();
  int tb = lin/12;  int k = lin - tb*12;
  int t  = tb >> 7; int b = tb & 127;
  const float* rowp = in + (size_t)br*inStrideBranch + ((size_t)b*TT + t)*D;
  float aI=bL[k], aF=bL[12+k], aG=bL[24+k], aO=bL[36+k];
  int nd4 = D >> 2;
  const float4* rp4 = (const float4*)rowp;
  for (int d4=0; d4<nd4; d4++){
    float4 xv = rp4[d4];
    float4 wI = *(const float4*)&wL[(0*12+k)*D + d4*4];
    float4 wF = *(const float4*)&wL[(1*12+k)*D + d4*4];
    float4 wG = *(const float4*)&wL[(2*12+k)*D + d4*4];
    float4 wO = *(const float4*)&wL[(3*12+k)*D + d4*4];
    aI += xv.x*wI.x + xv.y*wI.y + xv.z*wI.z + xv.w*wI.w;
    aF += xv.x*wF.x + xv.y*wF.y + xv.z*wF.z + xv.w*wF.w;
    aG += xv.x*wG.x + xv.y*wG.y + xv.z*wG.z + xv.w*wG.w;
    aO += xv.x*wO.x + xv.y*wO.y + xv.z*wO.z + xv.w*wO.w;
  }
  float4* o = (float4*)(pre + (size_t)r*(TT*BB*48) + (size_t)tb*48 + k*4);
  *o = make_float4(aI,aF,aG,aO);
}

// ---------------- K3: recurrent LSTM scan -------------------------------
// 1 wave/block, 4 batch x 16 lanes. pre staged through LDS in 16-step
// double-buffered chunks (loads issued a full chunk ahead). h-exchange via
// LDS write + b64 reads. Gate dots in packed f32 (v_pk_fma_f32).
__global__ __launch_bounds__(64,1) void lstm_kernel(const float* __restrict__ pre,
    const float* __restrict__ whhA, const float* __restrict__ whhB,
    float* __restrict__ out)
{
  int blk = blockIdx.x;
  int r   = blk >> 5;            // run 0..3
  int br  = r >> 1, dir = r & 1;
  int lane = threadIdx.x;
  int sub  = lane >> 4;
  int k    = lane & 15;
  int keff = (k < 12) ? k : 11;
  int b0   = (blk & 31)*4;
  const float* preR2 = pre + (size_t)r*(TT*BB*48) + b0*48;
  const float* whh   = (br ? whhB : whhA) + dir*48*12;
  float* outR = out + (size_t)br*(BB*TT*24) + (size_t)(b0+sub)*TT*24 + dir*12 + keff;

  v2f wi2[6], wf2[6], wg2[6], wo2[6];
  #pragma unroll
  for (int j=0;j<6;j++){
    wi2[j] = *(const v2f*)&whh[(    keff)*12 + 2*j];
    wf2[j] = *(const v2f*)&whh[(12+keff)*12 + 2*j];
    wg2[j] = *(const v2f*)&whh[(24+keff)*12 + 2*j];
    wo2[j] = *(const v2f*)&whh[(36+keff)*12 + 2*j];
  }

  __shared__ float chunkL[2][16*192];
  __shared__ float hx[64];

  int toff[12];
  #pragma unroll
  for (int i=0;i<12;i++){
    int f4i = i*64 + lane;
    int ssi = f4i/48;
    int offi = f4i - ssi*48;
    toff[i] = (dir ? -(ssi*6144) : (ssi*6144)) + offi*4;
  }
  int scb = dir ? 223*6144 : 0;
  const int scbd = dir ? -(16*6144) : (16*6144);

  float4 g[12];
  #pragma unroll
  for (int i=0;i<12;i++) g[i] = *(const float4*)(preR2 + (scb + toff[i]));
  #pragma unroll
  for (int i=0;i<12;i++) *(float4*)&chunkL[0][(i*64+lane)*4] = g[i];
  scb += scbd;
  #pragma unroll
  for (int i=0;i<12;i++) g[i] = *(const float4*)(preR2 + (scb + toff[i]));

  v2f h2[6];
  #pragma unroll
  for (int j=0;j<6;j++) h2[j] = (v2f)(0.0f);
  float cst = 0.f;
  float4 p4 = *(const float4*)&chunkL[0][sub*48 + keff*4];
  int t = dir ? (TT-1) : 0;
  const int tsgn = dir ? -1 : 1;
  const int lofs = sub*16;

  for (int c=0;c<14;++c){
    #pragma unroll
    for (int ss=0;ss<16;++ss){
      v2f ai = {p4.x, 0.f}, af = {p4.y, 0.f}, ag = {p4.z, 0.f}, ao = {p4.w, 0.f};
      #pragma unroll
      for (int j=0;j<6;j++){
        ai += wi2[j]*h2[j];
        af += wf2[j]*h2[j];
        ag += wg2[j]*h2[j];
        ao += wo2[j]*h2[j];
      }
      float gi=ai.x+ai.y, gf=af.x+af.y, gg=ag.x+ag.y, go=ao.x+ao.y;
      float si=sigmf(gi), sf=sigmf(gf), tg=tanhfast(gg), so=sigmf(go);
      cst = sf*cst + si*tg;
      float hv = so * tanhfast(cst);
      if (k < 12) outR[(size_t)t*24] = hv;
      hx[lane] = hv;                      // ds_write (k>=12 lanes write junk slots)
      if (ss==15 && c<13){
        // stage chunk c+1 (held in g[]) into the other buffer; kick off c+2 loads
        #pragma unroll
        for (int i=0;i<12;i++) *(float4*)&chunkL[(c+1)&1][(i*64+lane)*4] = g[i];
        scb += scbd;
        if (c<12){
          #pragma unroll
          for (int i=0;i<12;i++) g[i] = *(const float4*)(preR2 + (scb + toff[i]));
        }
      }
      if (!(c==13 && ss==15)){
        #pragma unroll
        for (int j=0;j<6;j++) h2[j] = *((const v2f*)&hx[lofs] + j);
        int nbuf = (ss==15) ? ((c+1)&1) : (c&1);
        int nss  = (ss+1)&15;
        p4 = *(const float4*)&chunkL[nbuf][nss*192 + sub*48 + keff*4];
      }
      t += tsgn;
    }
  }
}

// ---------------- K6a: Wt = W3(9,192) @ W2(192,1024) ----------------------
__global__ void wcomp1_kernel(const float* __restrict__ fcw3, const float* __restrict__ fcw2,
                              float* __restrict__ Wt)
{
  int idx = blockIdx.x*256+threadIdx.x;
  if (idx >= 9*1024) return;
  int o = idx >> 10;
  int n = idx & 1023;
  float acc = 0.f;
  for (int p=0;p<192;p++) acc += fcw3[o*192+p]*fcw2[p*1024+n];
  Wt[idx] = acc;
}

// ---------------- K6b-A: split-K partials  wpart[s][o][j] ------------------
__global__ void wpartA_kernel(const float* __restrict__ Wt, const float* __restrict__ fcw1,
                              float* __restrict__ wpart)
{
  int s  = blockIdx.x / 21;
  int jb = blockIdx.x % 21;
  int j  = jb*256 + threadIdx.x;      // < 5376
  __shared__ float wtL[9*64];
  for (int i=threadIdx.x;i<9*64;i+=256){
    int o=i>>6, n=i&63;
    wtL[i]=Wt[o*1024 + s*64 + n];
  }
  __syncthreads();
  float acc[9];
  #pragma unroll
  for (int o=0;o<9;o++) acc[o]=0.f;
  int nbase = s*64;
  for (int n=0;n<64;n++){
    float v = fcw1[(size_t)(nbase+n)*5376 + j];
    #pragma unroll
    for (int o=0;o<9;o++) acc[o] += wtL[o*64+n]*v;
  }
  #pragma unroll
  for (int o=0;o<9;o++) wpart[((size_t)s*9+o)*5376 + j] = acc[o];
}

// ---------------- K6b-B: Wc = sum_s wpart[s] ------------------------------
__global__ void wpartB_kernel(const float* __restrict__ wpart, float* __restrict__ Wc)
{
  int idx = blockIdx.x*256+threadIdx.x;     // 189 blocks = 48384
  if (idx >= 48384) return;
  float a = 0.f;
  #pragma unroll
  for (int s=0;s<16;s++) a += wpart[(size_t)s*48384 + idx];
  Wc[idx] = a;
}

// ---------------- K6b-C: composite bias BC --------------------------------
__global__ void bcomp_kernel(const float* __restrict__ Wt,
    const float* __restrict__ fcb1, const float* __restrict__ fcb2,
    const float* __restrict__ fcw3, const float* __restrict__ fcb3,
    float* __restrict__ BC)
{
  int o = blockIdx.x;           // 9 blocks, 64 threads
  int lane = threadIdx.x;
  float acc = 0.f;
  for (int p=lane;p<192;p+=64)  acc += fcw3[o*192+p]*fcb2[p];
  for (int n=lane;n<1024;n+=64) acc += Wt[o*1024+n]*fcb1[n];
  #pragma unroll
  for (int off=32;off;off>>=1) acc += __shfl_down(acc, off);
  if (lane==0) BC[o] = acc + fcb3[o];
}

// ---------------- K6c: out[m][o] = (w1*o1+w2*o2) . Wc[o] + BC[o] ----------
__global__ void final_kernel(const float* __restrict__ o1, const float* __restrict__ o2,
    const float* __restrict__ Wc, const float* __restrict__ BC,
    const float* __restrict__ w1p, const float* __restrict__ w2p,
    float* __restrict__ out)
{
  int wid  = blockIdx.x*4 + (threadIdx.x>>6);
  int lane = threadIdx.x & 63;
  if (wid >= 128*9) return;
  int m = wid / 9, o = wid - m*9;
  float w1 = w1p[0], w2 = w2p[0];
  const float* r1 = o1 + (size_t)m*5376;
  const float* r2 = o2 + (size_t)m*5376;
  const float* wc = Wc + (size_t)o*5376;
  float acc = 0.f;
  for (int i=lane;i<5376;i+=64){
    acc += (w1*r1[i] + w2*r2[i]) * wc[i];
  }
  #pragma unroll
  for (int off=32;off;off>>=1) acc += __shfl_down(acc, off);
  if (lane==0) out[m*9+o] = acc + BC[o];
}

extern "C" void kernel_launch(void* const* d_in, const int* in_sizes, int n_in,
                              void* d_out, int out_size, void* d_ws, size_t ws_size,
                              hipStream_t stream) {
  (void)in_sizes; (void)n_in; (void)out_size; (void)ws_size;
  const float* x    = (const float*)d_in[0];
  const float* c1w1 = (const float*)d_in[1];
  const float* c1b1 = (const float*)d_in[2];
  const float* c1w2 = (const float*)d_in[3];
  const float* c1b2 = (const float*)d_in[4];
  const float* c2w1 = (const float*)d_in[5];
  const float* c2b1 = (const float*)d_in[6];
  const float* c2w2 = (const float*)d_in[7];
  const float* c2b2 = (const float*)d_in[8];
  const float* l10Wih = (const float*)d_in[9];
  const float* l10Whh = (const float*)d_in[10];
  const float* l10b   = (const float*)d_in[11];
  const float* l11Wih = (const float*)d_in[12];
  const float* l11Whh = (const float*)d_in[13];
  const float* l11b   = (const float*)d_in[14];
  const float* l20Wih = (const float*)d_in[15];
  const float* l20Whh = (const float*)d_in[16];
  const float* l20b   = (const float*)d_in[17];
  const float* l21Wih = (const float*)d_in[18];
  const float* l21Whh = (const float*)d_in[19];
  const float* l21b   = (const float*)d_in[20];
  const float* fcw1 = (const float*)d_in[21];
  const float* fcb1 = (const float*)d_in[22];
  const float* fcw2 = (const float*)d_in[23];
  const float* fcb2 = (const float*)d_in[24];
  const float* fcw3 = (const float*)d_in[25];
  const float* fcb3 = (const float*)d_in[26];
  const float* w1   = (const float*)d_in[27];
  const float* w2   = (const float*)d_in[28];
  float* out = (float*)d_out;

  float* ws  = (float*)d_ws;
  float* y    = ws;                       // 2 * 802816  (dead after pregate #1)
  float* pre  = y   + 2*802816;           // 4 * 1376256
  float* ol0  = pre + 4*1376256;          // 2 * 688128
  float* ol1  = ol0 + 2*688128;           // 2 * 688128
  float* Wt   = ol1 + 2*688128;           // 9216
  float* Wc   = Wt  + 9216;               // 48384
  float* BC   = Wc  + 48384;              // 9
  float* wpart = y;                       // alias: 16*9*5376 = 774144 < 1605632

  conv_chain_kernel<<<6272,256,0,stream>>>(x, c1w1,c1b1,c1w2,c1b2, c2w1,c2b1,c2w2,c2b2, y);
  pregate_kernel<<<4*1344,256,0,stream>>>(y,   802816, 28, l10Wih, l10b, l20Wih, l20b, pre);
  lstm_kernel<<<128,64,0,stream>>>(pre, l10Whh, l20Whh, ol0);
  pregate_kernel<<<4*1344,256,0,stream>>>(ol0, 688128, 24, l11Wih, l11b, l21Wih, l21b, pre);
  lstm_kernel<<<128,64,0,stream>>>(pre, l11Whh, l21Whh, ol1);
  wcomp1_kernel<<<36,256,0,stream>>>(fcw3, fcw2, Wt);
  wpartA_kernel<<<336,256,0,stream>>>(Wt, fcw1, wpart);
  wpartB_kernel<<<189,256,0,stream>>>(wpart, Wc);
  bcomp_kernel<<<9,64,0,stream>>>(Wt, fcb1, fcb2, fcw3, fcb3, BC);
  final_kernel<<<288,256,0,stream>>>(ol1, ol1+688128, Wc, BC, w1, w2, out);
}

// Round 4
// 279.280 us; speedup vs baseline: 1.9869x; 1.1984x over previous
//
#include <hip/hip_runtime.h>

#define BB 128
#define TT 224
#define LL 224

typedef float v2f __attribute__((ext_vector_type(2)));

__device__ __forceinline__ float rcpf(float x){ return __builtin_amdgcn_rcpf(x); }
__device__ __forceinline__ float sigmf(float x){ return rcpf(1.0f + __expf(-x)); }
__device__ __forceinline__ float tanhfast(float x){ return 1.0f - 2.0f*rcpf(__expf(2.0f*x)+1.0f); }
// DPP row rotate-right by 1: dst[i] = src[(i-1)&15] within each 16-lane row
__device__ __forceinline__ float rotr1(float x){
  int xi = __builtin_bit_cast(int, x);
  xi = __builtin_amdgcn_update_dpp(xi, xi, 0x121, 0xf, 0xf, false);
  return __builtin_bit_cast(float, xi);
}

// ---------------- K1: conv chain, LDS-staged (both branches) ----------------
// block = 256 thr handles 4 rows of 224; 14336 blocks (7168 per branch)
__global__ __launch_bounds__(256) void conv_chain_kernel(const float* __restrict__ x,
    const float* __restrict__ c1w1, const float* __restrict__ c1b1,
    const float* __restrict__ c1w2, const float* __restrict__ c1b2,
    const float* __restrict__ c2w1, const float* __restrict__ c2b1,
    const float* __restrict__ c2w2, const float* __restrict__ c2b2,
    float* __restrict__ y)
{
  __shared__ float xs[4*224];
  __shared__ float c1s[4*56];
  int gid = blockIdx.x;
  int tid = threadIdx.x;
  int branch = (gid >= 7168);
  const float* w1 = branch ? c2w1 : c1w1;
  const float* w2 = branch ? c2w2 : c1w2;
  float b1  = branch ? c2b1[0] : c1b1[0];
  float b2v = branch ? c2b2[0] : c1b2[0];

  if (tid < 224){
    *(float4*)&xs[tid*4] = *((const float4*)x + (size_t)gid*224 + tid);
  }
  __syncthreads();
  if (tid < 224){
    int rr = tid / 56, cj = tid - rr*56;
    int base = 4*cj - 2;
    const float* xr = &xs[rr*224];
    float s = b1;
    #pragma unroll
    for (int kk=0;kk<8;kk++){
      int xi = base + kk;
      float xv = (xi>=0 && xi<224) ? xr[xi] : 0.f;
      s += xv * w1[kk];
    }
    c1s[rr*56 + cj] = fmaxf(s, 0.f);
  }
  __syncthreads();
  if (tid < 112){
    int rr = tid / 28, j = tid - rr*28;
    const float* cr = &c1s[rr*56];
    float o = b2v;
    #pragma unroll
    for (int pi=0;pi<3;pi++){
      int p = j - 1 + pi;
      float pool = 0.f;
      if (p>=0 && p<28){
        int i0 = 2*p - 1;
        float m = -1e30f;
        #pragma unroll
        for (int q=0;q<4;q++){
          int ii = i0+q;
          if (ii>=0 && ii<56) m = fmaxf(m, cr[ii]);
        }
        pool = fmaxf(m, 0.f);
      }
      o += pool * w2[pi];
    }
    y[(size_t)gid*112 + tid] = fmaxf(o, 0.f);
  }
}

// ---------------- K2: pre-gate GEMM (float4-vectorized) ----------------
__global__ void pregate_kernel(const float* __restrict__ in, int inStrideBranch, int D,
    const float* __restrict__ wihA, const float* __restrict__ biasA,
    const float* __restrict__ wihB, const float* __restrict__ biasB,
    float* __restrict__ pre)
{
  int r = blockIdx.x / 1344;
  int lin = (blockIdx.x % 1344)*256 + threadIdx.x;
  int br = r>>1, dir = r&1;
  const float* wih  = (br ? wihB  : wihA)  + dir*48*D;
  const float* bias = (br ? biasB : biasA) + dir*48;
  __shared__ float wL[48*28];
  __shared__ float bL[48];
  for (int i = threadIdx.x; i < 48*D; i += 256) wL[i]=wih[i];
  if (threadIdx.x < 48) bL[threadIdx.x]=bias[threadIdx.x];
  __syncthreads();
  int tb = lin/12;  int k = lin - tb*12;
  int t  = tb >> 7; int b = tb & 127;
  const float* rowp = in + (size_t)br*inStrideBranch + ((size_t)b*TT + t)*D;
  float aI=bL[k], aF=bL[12+k], aG=bL[24+k], aO=bL[36+k];
  int nd4 = D >> 2;
  const float4* rp4 = (const float4*)rowp;
  for (int d4=0; d4<nd4; d4++){
    float4 xv = rp4[d4];
    float4 wI = *(const float4*)&wL[(0*12+k)*D + d4*4];
    float4 wF = *(const float4*)&wL[(1*12+k)*D + d4*4];
    float4 wG = *(const float4*)&wL[(2*12+k)*D + d4*4];
    float4 wO = *(const float4*)&wL[(3*12+k)*D + d4*4];
    aI += xv.x*wI.x + xv.y*wI.y + xv.z*wI.z + xv.w*wI.w;
    aF += xv.x*wF.x + xv.y*wF.y + xv.z*wF.z + xv.w*wF.w;
    aG += xv.x*wG.x + xv.y*wG.y + xv.z*wG.z + xv.w*wG.w;
    aO += xv.x*wO.x + xv.y*wO.y + xv.z*wO.z + xv.w*wO.w;
  }
  float4* o = (float4*)(pre + (size_t)r*(TT*BB*48) + (size_t)tb*48 + k*4);
  *o = make_float4(aI,aF,aG,aO);
}

// ---------------- K3: recurrent LSTM scan, DPP-rotation h-exchange --------
// 1 wave/block, 4 batches x 16 lanes; pre LDS-staged in 8-step dbuf chunks.
// Per step: h broadcast via 15x row_ror:1 (in-register), gates accumulate
// during rotation with lane-prepermuted weights (j>=12 ghost taps = 0).
__global__ __launch_bounds__(64,1) void lstm_kernel(const float* __restrict__ pre,
    const float* __restrict__ whhA, const float* __restrict__ whhB,
    float* __restrict__ out)
{
  int blk = blockIdx.x;
  int r   = blk >> 5;            // run 0..3
  int br  = r >> 1, dir = r & 1;
  int lane = threadIdx.x;
  int sub  = lane >> 4;
  int k    = lane & 15;
  int keff = (k < 12) ? k : 11;
  int b0   = (blk & 31)*4;
  const float* preR2 = pre + (size_t)r*(TT*BB*48) + b0*48;
  const float* whh   = (br ? whhB : whhA) + dir*48*12;
  float* outR = out + (size_t)br*(BB*TT*24) + (size_t)(b0+sub)*TT*24 + dir*12 + keff;

  // rotation-ordered weights: at rotation rr, this lane holds h_{(k-rr)&15}
  float wi[16], wf[16], wg[16], wo[16];
  #pragma unroll
  for (int rr=0; rr<16; rr++){
    int j = (k - rr) & 15;
    bool v = (j < 12) && (k < 12);
    wi[rr] = v ? whh[(    k)*12 + j] : 0.f;
    wf[rr] = v ? whh[(12+k)*12 + j] : 0.f;
    wg[rr] = v ? whh[(24+k)*12 + j] : 0.f;
    wo[rr] = v ? whh[(36+k)*12 + j] : 0.f;
  }

  __shared__ float chunkL[2][8*192];

  int toff[6];
  #pragma unroll
  for (int i=0;i<6;i++){
    int f4i = i*64 + lane;
    int ssi = f4i / 48;
    int offi = f4i - ssi*48;
    toff[i] = (dir ? -(ssi*6144) : (ssi*6144)) + offi*4;
  }
  int scb = dir ? 223*6144 : 0;
  const int scbd = dir ? -(8*6144) : (8*6144);

  float4 g[6];
  #pragma unroll
  for (int i=0;i<6;i++) g[i] = *(const float4*)(preR2 + (scb + toff[i]));
  #pragma unroll
  for (int i=0;i<6;i++) *(float4*)&chunkL[0][(i*64+lane)*4] = g[i];
  scb += scbd;
  #pragma unroll
  for (int i=0;i<6;i++) g[i] = *(const float4*)(preR2 + (scb + toff[i]));

  float hv = 0.f, cst = 0.f;
  int t = dir ? 223 : 0;
  const int tsgn = dir ? -1 : 1;
  float4 p4 = *(const float4*)&chunkL[0][sub*48 + keff*4];

  for (int c=0;c<28;c++){
    int cur = c & 1;
    #pragma unroll
    for (int ss=0;ss<8;ss++){
      float gi = p4.x + wi[0]*hv;
      float gf = p4.y + wf[0]*hv;
      float gg = p4.z + wg[0]*hv;
      float go = p4.w + wo[0]*hv;
      float xv = hv;
      #pragma unroll
      for (int rr=1; rr<16; rr++){
        xv = rotr1(xv);
        gi += wi[rr]*xv;
        gf += wf[rr]*xv;
        gg += wg[rr]*xv;
        go += wo[rr]*xv;
      }
      float si=sigmf(gi), sf=sigmf(gf), tg=tanhfast(gg), so=sigmf(go);
      cst = sf*cst + si*tg;
      hv = so * tanhfast(cst);
      if (k < 12) outR[(size_t)t*24] = hv;
      t += tsgn;
      if (ss < 7){
        p4 = *(const float4*)&chunkL[cur][(ss+1)*192 + sub*48 + keff*4];
      }
    }
    if (c < 27){
      #pragma unroll
      for (int i=0;i<6;i++) *(float4*)&chunkL[cur^1][(i*64+lane)*4] = g[i];
      scb += scbd;
      if (c < 26){
        #pragma unroll
        for (int i=0;i<6;i++) g[i] = *(const float4*)(preR2 + (scb + toff[i]));
      }
      p4 = *(const float4*)&chunkL[cur^1][sub*48 + keff*4];
    }
  }
}

// ---------------- K6a: Wt = W3(9,192) @ W2(192,1024) ----------------------
__global__ void wcomp1_kernel(const float* __restrict__ fcw3, const float* __restrict__ fcw2,
                              float* __restrict__ Wt)
{
  int idx = blockIdx.x*256+threadIdx.x;
  if (idx >= 9*1024) return;
  int o = idx >> 10;
  int n = idx & 1023;
  float acc = 0.f;
  for (int p=0;p<192;p++) acc += fcw3[o*192+p]*fcw2[p*1024+n];
  Wt[idx] = acc;
}

// ---------------- K6b-A: split-K partials  wpart[s][o][j] ------------------
__global__ void wpartA_kernel(const float* __restrict__ Wt, const float* __restrict__ fcw1,
                              float* __restrict__ wpart)
{
  int s  = blockIdx.x / 21;
  int jb = blockIdx.x % 21;
  int j  = jb*256 + threadIdx.x;      // < 5376
  __shared__ float wtL[9*64];
  for (int i=threadIdx.x;i<9*64;i+=256){
    int o=i>>6, n=i&63;
    wtL[i]=Wt[o*1024 + s*64 + n];
  }
  __syncthreads();
  float acc[9];
  #pragma unroll
  for (int o=0;o<9;o++) acc[o]=0.f;
  int nbase = s*64;
  for (int n=0;n<64;n++){
    float v = fcw1[(size_t)(nbase+n)*5376 + j];
    #pragma unroll
    for (int o=0;o<9;o++) acc[o] += wtL[o*64+n]*v;
  }
  #pragma unroll
  for (int o=0;o<9;o++) wpart[((size_t)s*9+o)*5376 + j] = acc[o];
}

// ---------------- K6b-B: Wc = sum_s wpart[s] ------------------------------
__global__ void wpartB_kernel(const float* __restrict__ wpart, float* __restrict__ Wc)
{
  int idx = blockIdx.x*256+threadIdx.x;     // 189 blocks = 48384
  if (idx >= 48384) return;
  float a = 0.f;
  #pragma unroll
  for (int s=0;s<16;s++) a += wpart[(size_t)s*48384 + idx];
  Wc[idx] = a;
}

// ---------------- K6b-C: composite bias BC --------------------------------
__global__ void bcomp_kernel(const float* __restrict__ Wt,
    const float* __restrict__ fcb1, const float* __restrict__ fcb2,
    const float* __restrict__ fcw3, const float* __restrict__ fcb3,
    float* __restrict__ BC)
{
  int o = blockIdx.x;           // 9 blocks, 64 threads
  int lane = threadIdx.x;
  float acc = 0.f;
  for (int p=lane;p<192;p+=64)  acc += fcw3[o*192+p]*fcb2[p];
  for (int n=lane;n<1024;n+=64) acc += Wt[o*1024+n]*fcb1[n];
  #pragma unroll
  for (int off=32;off;off>>=1) acc += __shfl_down(acc, off);
  if (lane==0) BC[o] = acc + fcb3[o];
}

// ---------------- K6c: out[m][o] = (w1*o1+w2*o2) . Wc[o] + BC[o] ----------
__global__ void final_kernel(const float* __restrict__ o1, const float* __restrict__ o2,
    const float* __restrict__ Wc, const float* __restrict__ BC,
    const float* __restrict__ w1p, const float* __restrict__ w2p,
    float* __restrict__ out)
{
  int wid  = blockIdx.x*4 + (threadIdx.x>>6);
  int lane = threadIdx.x & 63;
  if (wid >= 128*9) return;
  int m = wid / 9, o = wid - m*9;
  float w1 = w1p[0], w2 = w2p[0];
  const float* r1 = o1 + (size_t)m*5376;
  const float* r2 = o2 + (size_t)m*5376;
  const float* wc = Wc + (size_t)o*5376;
  float acc = 0.f;
  for (int i=lane;i<5376;i+=64){
    acc += (w1*r1[i] + w2*r2[i]) * wc[i];
  }
  #pragma unroll
  for (int off=32;off;off>>=1) acc += __shfl_down(acc, off);
  if (lane==0) out[m*9+o] = acc + BC[o];
}

extern "C" void kernel_launch(void* const* d_in, const int* in_sizes, int n_in,
                              void* d_out, int out_size, void* d_ws, size_t ws_size,
                              hipStream_t stream) {
  (void)in_sizes; (void)n_in; (void)out_size; (void)ws_size;
  const float* x    = (const float*)d_in[0];
  const float* c1w1 = (const float*)d_in[1];
  const float* c1b1 = (const float*)d_in[2];
  const float* c1w2 = (const float*)d_in[3];
  const float* c1b2 = (const float*)d_in[4];
  const float* c2w1 = (const float*)d_in[5];
  const float* c2b1 = (const float*)d_in[6];
  const float* c2w2 = (const float*)d_in[7];
  const float* c2b2 = (const float*)d_in[8];
  const float* l10Wih = (const float*)d_in[9];
  const float* l10Whh = (const float*)d_in[10];
  const float* l10b   = (const float*)d_in[11];
  const float* l11Wih = (const float*)d_in[12];
  const float* l11Whh = (const float*)d_in[13];
  const float* l11b   = (const float*)d_in[14];
  const float* l20Wih = (const float*)d_in[15];
  const float* l20Whh = (const float*)d_in[16];
  const float* l20b   = (const float*)d_in[17];
  const float* l21Wih = (const float*)d_in[18];
  const float* l21Whh = (const float*)d_in[19];
  const float* l21b   = (const float*)d_in[20];
  const float* fcw1 = (const float*)d_in[21];
  const float* fcb1 = (const float*)d_in[22];
  const float* fcw2 = (const float*)d_in[23];
  const float* fcb2 = (const float*)d_in[24];
  const float* fcw3 = (const float*)d_in[25];
  const float* fcb3 = (const float*)d_in[26];
  const float* w1   = (const float*)d_in[27];
  const float* w2   = (const float*)d_in[28];
  float* out = (float*)d_out;

  float* ws  = (float*)d_ws;
  float* y    = ws;                       // 2 * 802816  (dead after pregate #1)
  float* pre  = y   + 2*802816;           // 4 * 1376256
  float* ol0  = pre + 4*1376256;          // 2 * 688128
  float* ol1  = ol0 + 2*688128;           // 2 * 688128
  float* Wt   = ol1 + 2*688128;           // 9216
  float* Wc   = Wt  + 9216;               // 48384
  float* BC   = Wc  + 48384;              // 9
  float* wpart = y;                       // alias: 16*9*5376 = 774144 < 1605632

  conv_chain_kernel<<<14336,256,0,stream>>>(x, c1w1,c1b1,c1w2,c1b2, c2w1,c2b1,c2w2,c2b2, y);
  pregate_kernel<<<4*1344,256,0,stream>>>(y,   802816, 28, l10Wih, l10b, l20Wih, l20b, pre);
  lstm_kernel<<<128,64,0,stream>>>(pre, l10Whh, l20Whh, ol0);
  pregate_kernel<<<4*1344,256,0,stream>>>(ol0, 688128, 24, l11Wih, l11b, l21Wih, l21b, pre);
  lstm_kernel<<<128,64,0,stream>>>(pre, l11Whh, l21Whh, ol1);
  wcomp1_kernel<<<36,256,0,stream>>>(fcw3, fcw2, Wt);
  wpartA_kernel<<<336,256,0,stream>>>(Wt, fcw1, wpart);
  wpartB_kernel<<<189,256,0,stream>>>(wpart, Wc);
  bcomp_kernel<<<9,64,0,stream>>>(Wt, fcb1, fcb2, fcw3, fcb3, BC);
  final_kernel<<<288,256,0,stream>>>(ol1, ol1+688128, Wc, BC, w1, w2, out);
}

// Round 5
// 224.013 us; speedup vs baseline: 2.4771x; 1.2467x over previous
//
#include <hip/hip_runtime.h>

#define BB 128
#define TT 224
#define LL 224

typedef float v2f __attribute__((ext_vector_type(2)));

__device__ __forceinline__ float rcpf(float x){ return __builtin_amdgcn_rcpf(x); }
__device__ __forceinline__ float sigmf(float x){ return rcpf(1.0f + __expf(-x)); }
__device__ __forceinline__ float tanhfast(float x){ return 1.0f - 2.0f*rcpf(__expf(2.0f*x)+1.0f); }

// DPP row rotate-right by N: dst[k] = src[(k-N)&15] within each 16-lane row
template<int N>
__device__ __forceinline__ float rorN(float x){
  int xi = __builtin_bit_cast(int, x);
  xi = __builtin_amdgcn_update_dpp(xi, xi, 0x120 + N, 0xf, 0xf, false);
  return __builtin_bit_cast(float, xi);
}

// ---------------- K1: conv chain, LDS-staged (both branches) ----------------
__global__ __launch_bounds__(256) void conv_chain_kernel(const float* __restrict__ x,
    const float* __restrict__ c1w1, const float* __restrict__ c1b1,
    const float* __restrict__ c1w2, const float* __restrict__ c1b2,
    const float* __restrict__ c2w1, const float* __restrict__ c2b1,
    const float* __restrict__ c2w2, const float* __restrict__ c2b2,
    float* __restrict__ y)
{
  __shared__ float xs[4*224];
  __shared__ float c1s[4*56];
  int gid = blockIdx.x;
  int tid = threadIdx.x;
  int branch = (gid >= 7168);
  const float* w1 = branch ? c2w1 : c1w1;
  const float* w2 = branch ? c2w2 : c1w2;
  float b1  = branch ? c2b1[0] : c1b1[0];
  float b2v = branch ? c2b2[0] : c1b2[0];

  if (tid < 224){
    *(float4*)&xs[tid*4] = *((const float4*)x + (size_t)gid*224 + tid);
  }
  __syncthreads();
  if (tid < 224){
    int rr = tid / 56, cj = tid - rr*56;
    int base = 4*cj - 2;
    const float* xr = &xs[rr*224];
    float s = b1;
    #pragma unroll
    for (int kk=0;kk<8;kk++){
      int xi = base + kk;
      float xv = (xi>=0 && xi<224) ? xr[xi] : 0.f;
      s += xv * w1[kk];
    }
    c1s[rr*56 + cj] = fmaxf(s, 0.f);
  }
  __syncthreads();
  if (tid < 112){
    int rr = tid / 28, j = tid - rr*28;
    const float* cr = &c1s[rr*56];
    float o = b2v;
    #pragma unroll
    for (int pi=0;pi<3;pi++){
      int p = j - 1 + pi;
      float pool = 0.f;
      if (p>=0 && p<28){
        int i0 = 2*p - 1;
        float m = -1e30f;
        #pragma unroll
        for (int q=0;q<4;q++){
          int ii = i0+q;
          if (ii>=0 && ii<56) m = fmaxf(m, cr[ii]);
        }
        pool = fmaxf(m, 0.f);
      }
      o += pool * w2[pi];
    }
    y[(size_t)gid*112 + tid] = fmaxf(o, 0.f);
  }
}

// ---------------- K2: pre-gate GEMM (templated D, fully unrolled) ----------
template<int D>
__global__ void pregate_kernel(const float* __restrict__ in, int inStrideBranch,
    const float* __restrict__ wihA, const float* __restrict__ biasA,
    const float* __restrict__ wihB, const float* __restrict__ biasB,
    float* __restrict__ pre)
{
  int r = blockIdx.x / 1344;
  int lin = (blockIdx.x % 1344)*256 + threadIdx.x;
  int br = r>>1, dir = r&1;
  const float* wih  = (br ? wihB  : wihA)  + dir*48*D;
  const float* bias = (br ? biasB : biasA) + dir*48;
  __shared__ float wL[48*D];
  __shared__ float bL[48];
  for (int i = threadIdx.x; i < 48*D; i += 256) wL[i]=wih[i];
  if (threadIdx.x < 48) bL[threadIdx.x]=bias[threadIdx.x];
  __syncthreads();
  int tb = lin/12;  int k = lin - tb*12;
  int t  = tb >> 7; int b = tb & 127;
  const float* rowp = in + (size_t)br*inStrideBranch + ((size_t)b*TT + t)*D;
  float aI=bL[k], aF=bL[12+k], aG=bL[24+k], aO=bL[36+k];
  const float4* rp4 = (const float4*)rowp;
  #pragma unroll
  for (int d4=0; d4<D/4; d4++){
    float4 xv = rp4[d4];
    float4 wI = *(const float4*)&wL[(0*12+k)*D + d4*4];
    float4 wF = *(const float4*)&wL[(1*12+k)*D + d4*4];
    float4 wG = *(const float4*)&wL[(2*12+k)*D + d4*4];
    float4 wO = *(const float4*)&wL[(3*12+k)*D + d4*4];
    aI += xv.x*wI.x + xv.y*wI.y + xv.z*wI.z + xv.w*wI.w;
    aF += xv.x*wF.x + xv.y*wF.y + xv.z*wF.z + xv.w*wF.w;
    aG += xv.x*wG.x + xv.y*wG.y + xv.z*wG.z + xv.w*wG.w;
    aO += xv.x*wO.x + xv.y*wO.y + xv.z*wO.z + xv.w*wO.w;
  }
  float4* o = (float4*)(pre + (size_t)r*(TT*BB*48) + (size_t)tb*48 + k*4);
  *o = make_float4(aI,aF,aG,aO);
}

// ---------------- K3: recurrent LSTM scan, all-register ------------------
// 1 wave/block forced to sole occupancy (full VGPR file). 4 batches x 16
// lanes. pre read directly global->reg, double-buffered 8-step banks.
// h-broadcast: 15 independent row_ror:N DPP gathers. Gates in packed f32.
#define TAP(N) { float xr_ = rorN<N>(hv); \
  aIF += wIF[N]*(v2f){xr_,xr_}; aGO += wGO[N]*(v2f){xr_,xr_}; }

#define LSTM_STEP(P) { \
  v2f aIF; aIF.x = (P).x; aIF.y = (P).y; \
  v2f aGO; aGO.x = (P).z; aGO.y = (P).w; \
  aIF += wIF[0]*(v2f){hv,hv}; aGO += wGO[0]*(v2f){hv,hv}; \
  TAP(1) TAP(2) TAP(3) TAP(4) TAP(5) TAP(6) TAP(7) TAP(8) \
  TAP(9) TAP(10) TAP(11) TAP(12) TAP(13) TAP(14) TAP(15) \
  float si=sigmf(aIF.x), sf=sigmf(aIF.y), tg=tanhfast(aGO.x), so=sigmf(aGO.y); \
  cst = sf*cst + si*tg; \
  hv = so * tanhfast(cst); \
  if (k < 12) *outP = hv; \
  outP += ostep; }

__global__ __launch_bounds__(64) __attribute__((amdgpu_waves_per_eu(1,1)))
void lstm_kernel(const float* __restrict__ pre,
    const float* __restrict__ whhA, const float* __restrict__ whhB,
    float* __restrict__ out)
{
  int blk = blockIdx.x;
  int r   = blk >> 5;            // run 0..3
  int br  = r >> 1, dir = r & 1;
  int lane = threadIdx.x;
  int sub  = lane >> 4;
  int k    = lane & 15;
  int keff = (k < 12) ? k : 11;
  int b0   = (blk & 31)*4;
  const float* preR2 = pre + (size_t)r*(TT*BB*48) + b0*48;
  const float* whh   = (br ? whhB : whhA) + dir*48*12;
  float* outR = out + (size_t)br*(BB*TT*24) + (size_t)(b0+sub)*TT*24 + dir*12 + keff;

  // rotation-ordered packed weights: at rotation rr, lane k holds h_{(k-rr)&15}
  v2f wIF[16], wGO[16];
  #pragma unroll
  for (int rr=0; rr<16; rr++){
    int j  = (k - rr) & 15;
    bool v = (j < 12) && (k < 12);
    int kw = (k < 12) ? k : 0;
    int jw = (j < 12) ? j : 0;
    float a  = whh[(    kw)*12 + jw];
    float bb = whh[(12+kw)*12 + jw];
    float cc = whh[(24+kw)*12 + jw];
    float dd = whh[(36+kw)*12 + jw];
    wIF[rr] = (v2f){ v ? a : 0.f,  v ? bb : 0.f };
    wGO[rr] = (v2f){ v ? cc : 0.f, v ? dd : 0.f };
  }

  const int laneoff = sub*48 + keff*4;
  const int sstep   = dir ? -6144 : 6144;     // float stride per t
  int scb = dir ? 223*6144 : 0;

  float4 pcur[8], pnext[8];
  #pragma unroll
  for (int i=0;i<8;i++) pcur[i]  = *(const float4*)(preR2 + scb +  i      *sstep + laneoff);
  #pragma unroll
  for (int i=0;i<8;i++) pnext[i] = *(const float4*)(preR2 + scb + (i + 8) *sstep + laneoff);
  int lb = scb + 16*sstep;

  float hv = 0.f, cst = 0.f;
  const int ostep = dir ? -24 : 24;
  float* outP = outR + (dir ? 223 : 0)*24;

  for (int c=0;c<14;c++){
    #pragma unroll
    for (int ss=0; ss<8; ss++){ LSTM_STEP(pcur[ss]); }
    if (c < 13){
      #pragma unroll
      for (int i=0;i<8;i++) pcur[i] = *(const float4*)(preR2 + lb + i*sstep + laneoff);
      lb += 8*sstep;
    }
    #pragma unroll
    for (int ss=0; ss<8; ss++){ LSTM_STEP(pnext[ss]); }
    if (c < 13){
      #pragma unroll
      for (int i=0;i<8;i++) pnext[i] = *(const float4*)(preR2 + lb + i*sstep + laneoff);
      lb += 8*sstep;
    }
  }
}

// ---------------- K6a: Wt = W3(9,192) @ W2(192,1024) ----------------------
__global__ void wcomp1_kernel(const float* __restrict__ fcw3, const float* __restrict__ fcw2,
                              float* __restrict__ Wt)
{
  int idx = blockIdx.x*256+threadIdx.x;
  if (idx >= 9*1024) return;
  int o = idx >> 10;
  int n = idx & 1023;
  float acc = 0.f;
  for (int p=0;p<192;p++) acc += fcw3[o*192+p]*fcw2[p*1024+n];
  Wt[idx] = acc;
}

// ---------------- K6b-A: split-K partials  wpart[s][o][j] ------------------
__global__ void wpartA_kernel(const float* __restrict__ Wt, const float* __restrict__ fcw1,
                              float* __restrict__ wpart)
{
  int s  = blockIdx.x / 21;
  int jb = blockIdx.x % 21;
  int j  = jb*256 + threadIdx.x;      // < 5376
  __shared__ float wtL[9*64];
  for (int i=threadIdx.x;i<9*64;i+=256){
    int o=i>>6, n=i&63;
    wtL[i]=Wt[o*1024 + s*64 + n];
  }
  __syncthreads();
  float acc[9];
  #pragma unroll
  for (int o=0;o<9;o++) acc[o]=0.f;
  int nbase = s*64;
  for (int n=0;n<64;n++){
    float v = fcw1[(size_t)(nbase+n)*5376 + j];
    #pragma unroll
    for (int o=0;o<9;o++) acc[o] += wtL[o*64+n]*v;
  }
  #pragma unroll
  for (int o=0;o<9;o++) wpart[((size_t)s*9+o)*5376 + j] = acc[o];
}

// ---------------- K6b-B: Wc = sum_s wpart[s] ------------------------------
__global__ void wpartB_kernel(const float* __restrict__ wpart, float* __restrict__ Wc)
{
  int idx = blockIdx.x*256+threadIdx.x;     // 189 blocks = 48384
  if (idx >= 48384) return;
  float a = 0.f;
  #pragma unroll
  for (int s=0;s<16;s++) a += wpart[(size_t)s*48384 + idx];
  Wc[idx] = a;
}

// ---------------- K6b-C: composite bias BC --------------------------------
__global__ void bcomp_kernel(const float* __restrict__ Wt,
    const float* __restrict__ fcb1, const float* __restrict__ fcb2,
    const float* __restrict__ fcw3, const float* __restrict__ fcb3,
    float* __restrict__ BC)
{
  int o = blockIdx.x;           // 9 blocks, 64 threads
  int lane = threadIdx.x;
  float acc = 0.f;
  for (int p=lane;p<192;p+=64)  acc += fcw3[o*192+p]*fcb2[p];
  for (int n=lane;n<1024;n+=64) acc += Wt[o*1024+n]*fcb1[n];
  #pragma unroll
  for (int off=32;off;off>>=1) acc += __shfl_down(acc, off);
  if (lane==0) BC[o] = acc + fcb3[o];
}

// ---------------- K6c: out[m][o] = (w1*o1+w2*o2) . Wc[o] + BC[o] ----------
__global__ void final_kernel(const float* __restrict__ o1, const float* __restrict__ o2,
    const float* __restrict__ Wc, const float* __restrict__ BC,
    const float* __restrict__ w1p, const float* __restrict__ w2p,
    float* __restrict__ out)
{
  int wid  = blockIdx.x*4 + (threadIdx.x>>6);
  int lane = threadIdx.x & 63;
  if (wid >= 128*9) return;
  int m = wid / 9, o = wid - m*9;
  float w1 = w1p[0], w2 = w2p[0];
  const float* r1 = o1 + (size_t)m*5376;
  const float* r2 = o2 + (size_t)m*5376;
  const float* wc = Wc + (size_t)o*5376;
  float acc = 0.f;
  for (int i=lane;i<5376;i+=64){
    acc += (w1*r1[i] + w2*r2[i]) * wc[i];
  }
  #pragma unroll
  for (int off=32;off;off>>=1) acc += __shfl_down(acc, off);
  if (lane==0) out[m*9+o] = acc + BC[o];
}

extern "C" void kernel_launch(void* const* d_in, const int* in_sizes, int n_in,
                              void* d_out, int out_size, void* d_ws, size_t ws_size,
                              hipStream_t stream) {
  (void)in_sizes; (void)n_in; (void)out_size; (void)ws_size;
  const float* x    = (const float*)d_in[0];
  const float* c1w1 = (const float*)d_in[1];
  const float* c1b1 = (const float*)d_in[2];
  const float* c1w2 = (const float*)d_in[3];
  const float* c1b2 = (const float*)d_in[4];
  const float* c2w1 = (const float*)d_in[5];
  const float* c2b1 = (const float*)d_in[6];
  const float* c2w2 = (const float*)d_in[7];
  const float* c2b2 = (const float*)d_in[8];
  const float* l10Wih = (const float*)d_in[9];
  const float* l10Whh = (const float*)d_in[10];
  const float* l10b   = (const float*)d_in[11];
  const float* l11Wih = (const float*)d_in[12];
  const float* l11Whh = (const float*)d_in[13];
  const float* l11b   = (const float*)d_in[14];
  const float* l20Wih = (const float*)d_in[15];
  const float* l20Whh = (const float*)d_in[16];
  const float* l20b   = (const float*)d_in[17];
  const float* l21Wih = (const float*)d_in[18];
  const float* l21Whh = (const float*)d_in[19];
  const float* l21b   = (const float*)d_in[20];
  const float* fcw1 = (const float*)d_in[21];
  const float* fcb1 = (const float*)d_in[22];
  const float* fcw2 = (const float*)d_in[23];
  const float* fcb2 = (const float*)d_in[24];
  const float* fcw3 = (const float*)d_in[25];
  const float* fcb3 = (const float*)d_in[26];
  const float* w1   = (const float*)d_in[27];
  const float* w2   = (const float*)d_in[28];
  float* out = (float*)d_out;

  float* ws  = (float*)d_ws;
  float* y    = ws;                       // 2 * 802816  (dead after pregate #1)
  float* pre  = y   + 2*802816;           // 4 * 1376256
  float* ol0  = pre + 4*1376256;          // 2 * 688128
  float* ol1  = ol0 + 2*688128;           // 2 * 688128
  float* Wt   = ol1 + 2*688128;           // 9216
  float* Wc   = Wt  + 9216;               // 48384
  float* BC   = Wc  + 48384;              // 9
  float* wpart = y;                       // alias: 16*9*5376 = 774144 < 1605632

  conv_chain_kernel<<<14336,256,0,stream>>>(x, c1w1,c1b1,c1w2,c1b2, c2w1,c2b1,c2w2,c2b2, y);
  pregate_kernel<28><<<4*1344,256,0,stream>>>(y,   802816, l10Wih, l10b, l20Wih, l20b, pre);
  lstm_kernel<<<128,64,0,stream>>>(pre, l10Whh, l20Whh, ol0);
  pregate_kernel<24><<<4*1344,256,0,stream>>>(ol0, 688128, l11Wih, l11b, l21Wih, l21b, pre);
  lstm_kernel<<<128,64,0,stream>>>(pre, l11Whh, l21Whh, ol1);
  wcomp1_kernel<<<36,256,0,stream>>>(fcw3, fcw2, Wt);
  wpartA_kernel<<<336,256,0,stream>>>(Wt, fcw1, wpart);
  wpartB_kernel<<<189,256,0,stream>>>(wpart, Wc);
  bcomp_kernel<<<9,64,0,stream>>>(Wt, fcb1, fcb2, fcw3, fcb3, BC);
  final_kernel<<<288,256,0,stream>>>(ol1, ol1+688128, Wc, BC, w1, w2, out);
}

// Round 6
// 206.235 us; speedup vs baseline: 2.6906x; 1.0862x over previous
//
#include <hip/hip_runtime.h>

#define BB 128
#define TT 224
#define LL 224

typedef float v2f __attribute__((ext_vector_type(2)));

__device__ __forceinline__ float rcpf(float x){ return __builtin_amdgcn_rcpf(x); }
__device__ __forceinline__ float sigmf(float x){ return rcpf(1.0f + __expf(-x)); }
__device__ __forceinline__ float tanhfast(float x){ return 1.0f - 2.0f*rcpf(__expf(2.0f*x)+1.0f); }

// DPP row rotate-right by N: dst[k] = src[(k-N)&15] within each 16-lane row
template<int N>
__device__ __forceinline__ float rorN(float x){
  int xi = __builtin_bit_cast(int, x);
  xi = __builtin_amdgcn_update_dpp(xi, xi, 0x120 + N, 0xf, 0xf, false);
  return __builtin_bit_cast(float, xi);
}

// ---------------- K1: conv chain, LDS-staged (both branches) ----------------
__global__ __launch_bounds__(256) void conv_chain_kernel(const float* __restrict__ x,
    const float* __restrict__ c1w1, const float* __restrict__ c1b1,
    const float* __restrict__ c1w2, const float* __restrict__ c1b2,
    const float* __restrict__ c2w1, const float* __restrict__ c2b1,
    const float* __restrict__ c2w2, const float* __restrict__ c2b2,
    float* __restrict__ y)
{
  __shared__ float xs[4*224];
  __shared__ float c1s[4*56];
  int gid = blockIdx.x;
  int tid = threadIdx.x;
  int branch = (gid >= 7168);
  const float* w1 = branch ? c2w1 : c1w1;
  const float* w2 = branch ? c2w2 : c1w2;
  float b1  = branch ? c2b1[0] : c1b1[0];
  float b2v = branch ? c2b2[0] : c1b2[0];

  if (tid < 224){
    *(float4*)&xs[tid*4] = *((const float4*)x + (size_t)gid*224 + tid);
  }
  __syncthreads();
  if (tid < 224){
    int rr = tid / 56, cj = tid - rr*56;
    int base = 4*cj - 2;
    const float* xr = &xs[rr*224];
    float s = b1;
    #pragma unroll
    for (int kk=0;kk<8;kk++){
      int xi = base + kk;
      float xv = (xi>=0 && xi<224) ? xr[xi] : 0.f;
      s += xv * w1[kk];
    }
    c1s[rr*56 + cj] = fmaxf(s, 0.f);
  }
  __syncthreads();
  if (tid < 112){
    int rr = tid / 28, j = tid - rr*28;
    const float* cr = &c1s[rr*56];
    float o = b2v;
    #pragma unroll
    for (int pi=0;pi<3;pi++){
      int p = j - 1 + pi;
      float pool = 0.f;
      if (p>=0 && p<28){
        int i0 = 2*p - 1;
        float m = -1e30f;
        #pragma unroll
        for (int q=0;q<4;q++){
          int ii = i0+q;
          if (ii>=0 && ii<56) m = fmaxf(m, cr[ii]);
        }
        pool = fmaxf(m, 0.f);
      }
      o += pool * w2[pi];
    }
    y[(size_t)gid*112 + tid] = fmaxf(o, 0.f);
  }
}

// ---------------- K2: pre-gate GEMM (templated D, fully unrolled) ----------
template<int D>
__global__ void pregate_kernel(const float* __restrict__ in, int inStrideBranch,
    const float* __restrict__ wihA, const float* __restrict__ biasA,
    const float* __restrict__ wihB, const float* __restrict__ biasB,
    float* __restrict__ pre)
{
  int r = blockIdx.x / 1344;
  int lin = (blockIdx.x % 1344)*256 + threadIdx.x;
  int br = r>>1, dir = r&1;
  const float* wih  = (br ? wihB  : wihA)  + dir*48*D;
  const float* bias = (br ? biasB : biasA) + dir*48;
  __shared__ float wL[48*D];
  __shared__ float bL[48];
  for (int i = threadIdx.x; i < 48*D; i += 256) wL[i]=wih[i];
  if (threadIdx.x < 48) bL[threadIdx.x]=bias[threadIdx.x];
  __syncthreads();
  int tb = lin/12;  int k = lin - tb*12;
  int t  = tb >> 7; int b = tb & 127;
  const float* rowp = in + (size_t)br*inStrideBranch + ((size_t)b*TT + t)*D;
  float aI=bL[k], aF=bL[12+k], aG=bL[24+k], aO=bL[36+k];
  const float4* rp4 = (const float4*)rowp;
  #pragma unroll
  for (int d4=0; d4<D/4; d4++){
    float4 xv = rp4[d4];
    float4 wI = *(const float4*)&wL[(0*12+k)*D + d4*4];
    float4 wF = *(const float4*)&wL[(1*12+k)*D + d4*4];
    float4 wG = *(const float4*)&wL[(2*12+k)*D + d4*4];
    float4 wO = *(const float4*)&wL[(3*12+k)*D + d4*4];
    aI += xv.x*wI.x + xv.y*wI.y + xv.z*wI.z + xv.w*wI.w;
    aF += xv.x*wF.x + xv.y*wF.y + xv.z*wF.z + xv.w*wF.w;
    aG += xv.x*wG.x + xv.y*wG.y + xv.z*wG.z + xv.w*wG.w;
    aO += xv.x*wO.x + xv.y*wO.y + xv.z*wO.z + xv.w*wO.w;
  }
  float4* o = (float4*)(pre + (size_t)r*(TT*BB*48) + (size_t)tb*48 + k*4);
  *o = make_float4(aI,aF,aG,aO);
}

// ---------------- K3: recurrent LSTM scan, all-register ------------------
// 1 wave/block, sole occupancy, full VGPR file. 4 batches x 16 lanes.
// pre: global->reg, 8-step double-buffered banks. h-broadcast: 15
// independent row_ror DPPs. Gate dots: 4 independent 4-deep pk-FMA chains
// + 2-level tree (short dep chain). Output stores batched 8/group so the
// in-order vmcnt stream never puts a store wait on the critical path.
#define TAPS \
  float x1=rorN<1>(hv), x2=rorN<2>(hv), x3=rorN<3>(hv), x4=rorN<4>(hv), \
        x5=rorN<5>(hv), x6=rorN<6>(hv), x7=rorN<7>(hv), x8=rorN<8>(hv), \
        x9=rorN<9>(hv), x10=rorN<10>(hv), x11=rorN<11>(hv), x12=rorN<12>(hv), \
        x13=rorN<13>(hv), x14=rorN<14>(hv), x15=rorN<15>(hv);

#define GATEACC(W, BX, BY, R) { \
  v2f a0 = {BX, BY}; \
  a0 += W[0]*(v2f){hv,hv};   a0 += W[1]*(v2f){x1,x1};   a0 += W[2]*(v2f){x2,x2};   a0 += W[3]*(v2f){x3,x3}; \
  v2f a1 = W[4]*(v2f){x4,x4};   a1 += W[5]*(v2f){x5,x5};   a1 += W[6]*(v2f){x6,x6};   a1 += W[7]*(v2f){x7,x7}; \
  v2f a2 = W[8]*(v2f){x8,x8};   a2 += W[9]*(v2f){x9,x9};   a2 += W[10]*(v2f){x10,x10}; a2 += W[11]*(v2f){x11,x11}; \
  v2f a3 = W[12]*(v2f){x12,x12}; a3 += W[13]*(v2f){x13,x13}; a3 += W[14]*(v2f){x14,x14}; a3 += W[15]*(v2f){x15,x15}; \
  R = (a0+a1)+(a2+a3); }

#define LSTM_STEP(P, SS) { \
  TAPS \
  v2f aIF, aGO; \
  GATEACC(wIF, (P).x, (P).y, aIF) \
  GATEACC(wGO, (P).z, (P).w, aGO) \
  float si=sigmf(aIF.x), sf=sigmf(aIF.y), tg=tanhfast(aGO.x), so=sigmf(aGO.y); \
  cst = sf*cst + si*tg; \
  hv = so * tanhfast(cst); \
  hbuf[SS] = hv; }

#define FLUSH8 { \
  if (k < 12){ \
    _Pragma("unroll") \
    for (int q=0;q<8;q++) outP[q*ostep] = hbuf[q]; \
  } \
  outP += 8*ostep; }

__global__ __launch_bounds__(64) __attribute__((amdgpu_waves_per_eu(1,1)))
void lstm_kernel(const float* __restrict__ pre,
    const float* __restrict__ whhA, const float* __restrict__ whhB,
    float* __restrict__ out)
{
  int blk = blockIdx.x;
  int r   = blk >> 5;            // run 0..3
  int br  = r >> 1, dir = r & 1;
  int lane = threadIdx.x;
  int sub  = lane >> 4;
  int k    = lane & 15;
  int keff = (k < 12) ? k : 11;
  int b0   = (blk & 31)*4;
  const float* preR2 = pre + (size_t)r*(TT*BB*48) + b0*48;
  const float* whh   = (br ? whhB : whhA) + dir*48*12;

  // rotation-ordered packed weights: at rotation rr, lane k holds h_{(k-rr)&15}
  v2f wIF[16], wGO[16];
  #pragma unroll
  for (int rr=0; rr<16; rr++){
    int j  = (k - rr) & 15;
    bool v = (j < 12) && (k < 12);
    int kw = (k < 12) ? k : 0;
    int jw = (j < 12) ? j : 0;
    float a  = whh[(    kw)*12 + jw];
    float bb = whh[(12+kw)*12 + jw];
    float cc = whh[(24+kw)*12 + jw];
    float dd = whh[(36+kw)*12 + jw];
    wIF[rr] = (v2f){ v ? a : 0.f,  v ? bb : 0.f };
    wGO[rr] = (v2f){ v ? cc : 0.f, v ? dd : 0.f };
  }

  const int laneoff = sub*48 + keff*4;
  const int sstep   = dir ? -6144 : 6144;     // float stride per t
  int scb = dir ? 223*6144 : 0;

  float4 pcur[8], pnext[8];
  #pragma unroll
  for (int i=0;i<8;i++) pcur[i]  = *(const float4*)(preR2 + scb +  i      *sstep + laneoff);
  #pragma unroll
  for (int i=0;i<8;i++) pnext[i] = *(const float4*)(preR2 + scb + (i + 8) *sstep + laneoff);
  int lb = scb + 16*sstep;

  float hv = 0.f, cst = 0.f;
  float hbuf[8];
  const int ostep = dir ? -24 : 24;
  float* outP = out + (size_t)br*(BB*TT*24) + (size_t)(b0+sub)*TT*24 + dir*12 + keff
                    + (size_t)(dir ? 223 : 0)*24;

  for (int c=0;c<14;c++){
    LSTM_STEP(pcur[0],0) LSTM_STEP(pcur[1],1) LSTM_STEP(pcur[2],2) LSTM_STEP(pcur[3],3)
    LSTM_STEP(pcur[4],4) LSTM_STEP(pcur[5],5) LSTM_STEP(pcur[6],6) LSTM_STEP(pcur[7],7)
    FLUSH8
    if (c < 13){
      #pragma unroll
      for (int i=0;i<8;i++) pcur[i] = *(const float4*)(preR2 + lb + i*sstep + laneoff);
      lb += 8*sstep;
    }
    LSTM_STEP(pnext[0],0) LSTM_STEP(pnext[1],1) LSTM_STEP(pnext[2],2) LSTM_STEP(pnext[3],3)
    LSTM_STEP(pnext[4],4) LSTM_STEP(pnext[5],5) LSTM_STEP(pnext[6],6) LSTM_STEP(pnext[7],7)
    FLUSH8
    if (c < 13){
      #pragma unroll
      for (int i=0;i<8;i++) pnext[i] = *(const float4*)(preR2 + lb + i*sstep + laneoff);
      lb += 8*sstep;
    }
  }
}

// ---------------- K6a: Wt = W3(9,192) @ W2(192,1024) ----------------------
__global__ void wcomp1_kernel(const float* __restrict__ fcw3, const float* __restrict__ fcw2,
                              float* __restrict__ Wt)
{
  int idx = blockIdx.x*256+threadIdx.x;
  if (idx >= 9*1024) return;
  int o = idx >> 10;
  int n = idx & 1023;
  float acc = 0.f;
  for (int p=0;p<192;p++) acc += fcw3[o*192+p]*fcw2[p*1024+n];
  Wt[idx] = acc;
}

// ---------------- K6b-A: split-K partials  wpart[s][o][j] ------------------
__global__ void wpartA_kernel(const float* __restrict__ Wt, const float* __restrict__ fcw1,
                              float* __restrict__ wpart)
{
  int s  = blockIdx.x / 21;
  int jb = blockIdx.x % 21;
  int j  = jb*256 + threadIdx.x;      // < 5376
  __shared__ float wtL[9*64];
  for (int i=threadIdx.x;i<9*64;i+=256){
    int o=i>>6, n=i&63;
    wtL[i]=Wt[o*1024 + s*64 + n];
  }
  __syncthreads();
  float acc[9];
  #pragma unroll
  for (int o=0;o<9;o++) acc[o]=0.f;
  int nbase = s*64;
  for (int n=0;n<64;n++){
    float v = fcw1[(size_t)(nbase+n)*5376 + j];
    #pragma unroll
    for (int o=0;o<9;o++) acc[o] += wtL[o*64+n]*v;
  }
  #pragma unroll
  for (int o=0;o<9;o++) wpart[((size_t)s*9+o)*5376 + j] = acc[o];
}

// ---------------- K6b-B: Wc = sum_s wpart[s] ------------------------------
__global__ void wpartB_kernel(const float* __restrict__ wpart, float* __restrict__ Wc)
{
  int idx = blockIdx.x*256+threadIdx.x;     // 189 blocks = 48384
  if (idx >= 48384) return;
  float a = 0.f;
  #pragma unroll
  for (int s=0;s<16;s++) a += wpart[(size_t)s*48384 + idx];
  Wc[idx] = a;
}

// ---------------- K6b-C: composite bias BC --------------------------------
__global__ void bcomp_kernel(const float* __restrict__ Wt,
    const float* __restrict__ fcb1, const float* __restrict__ fcb2,
    const float* __restrict__ fcw3, const float* __restrict__ fcb3,
    float* __restrict__ BC)
{
  int o = blockIdx.x;           // 9 blocks, 64 threads
  int lane = threadIdx.x;
  float acc = 0.f;
  for (int p=lane;p<192;p+=64)  acc += fcw3[o*192+p]*fcb2[p];
  for (int n=lane;n<1024;n+=64) acc += Wt[o*1024+n]*fcb1[n];
  #pragma unroll
  for (int off=32;off;off>>=1) acc += __shfl_down(acc, off);
  if (lane==0) BC[o] = acc + fcb3[o];
}

// ---------------- K6c: out[m][o] = (w1*o1+w2*o2) . Wc[o] + BC[o] ----------
__global__ void final_kernel(const float* __restrict__ o1, const float* __restrict__ o2,
    const float* __restrict__ Wc, const float* __restrict__ BC,
    const float* __restrict__ w1p, const float* __restrict__ w2p,
    float* __restrict__ out)
{
  int wid  = blockIdx.x*4 + (threadIdx.x>>6);
  int lane = threadIdx.x & 63;
  if (wid >= 128*9) return;
  int m = wid / 9, o = wid - m*9;
  float w1 = w1p[0], w2 = w2p[0];
  const float* r1 = o1 + (size_t)m*5376;
  const float* r2 = o2 + (size_t)m*5376;
  const float* wc = Wc + (size_t)o*5376;
  float acc = 0.f;
  for (int i=lane;i<5376;i+=64){
    acc += (w1*r1[i] + w2*r2[i]) * wc[i];
  }
  #pragma unroll
  for (int off=32;off;off>>=1) acc += __shfl_down(acc, off);
  if (lane==0) out[m*9+o] = acc + BC[o];
}

extern "C" void kernel_launch(void* const* d_in, const int* in_sizes, int n_in,
                              void* d_out, int out_size, void* d_ws, size_t ws_size,
                              hipStream_t stream) {
  (void)in_sizes; (void)n_in; (void)out_size; (void)ws_size;
  const float* x    = (const float*)d_in[0];
  const float* c1w1 = (const float*)d_in[1];
  const float* c1b1 = (const float*)d_in[2];
  const float* c1w2 = (const float*)d_in[3];
  const float* c1b2 = (const float*)d_in[4];
  const float* c2w1 = (const float*)d_in[5];
  const float* c2b1 = (const float*)d_in[6];
  const float* c2w2 = (const float*)d_in[7];
  const float* c2b2 = (const float*)d_in[8];
  const float* l10Wih = (const float*)d_in[9];
  const float* l10Whh = (const float*)d_in[10];
  const float* l10b   = (const float*)d_in[11];
  const float* l11Wih = (const float*)d_in[12];
  const float* l11Whh = (const float*)d_in[13];
  const float* l11b   = (const float*)d_in[14];
  const float* l20Wih = (const float*)d_in[15];
  const float* l20Whh = (const float*)d_in[16];
  const float* l20b   = (const float*)d_in[17];
  const float* l21Wih = (const float*)d_in[18];
  const float* l21Whh = (const float*)d_in[19];
  const float* l21b   = (const float*)d_in[20];
  const float* fcw1 = (const float*)d_in[21];
  const float* fcb1 = (const float*)d_in[22];
  const float* fcw2 = (const float*)d_in[23];
  const float* fcb2 = (const float*)d_in[24];
  const float* fcw3 = (const float*)d_in[25];
  const float* fcb3 = (const float*)d_in[26];
  const float* w1   = (const float*)d_in[27];
  const float* w2   = (const float*)d_in[28];
  float* out = (float*)d_out;

  float* ws  = (float*)d_ws;
  float* y    = ws;                       // 2 * 802816  (dead after pregate #1)
  float* pre  = y   + 2*802816;           // 4 * 1376256
  float* ol0  = pre + 4*1376256;          // 2 * 688128
  float* ol1  = ol0 + 2*688128;           // 2 * 688128
  float* Wt   = ol1 + 2*688128;           // 9216
  float* Wc   = Wt  + 9216;               // 48384
  float* BC   = Wc  + 48384;              // 9
  float* wpart = y;                       // alias: 16*9*5376 = 774144 < 1605632

  conv_chain_kernel<<<14336,256,0,stream>>>(x, c1w1,c1b1,c1w2,c1b2, c2w1,c2b1,c2w2,c2b2, y);
  pregate_kernel<28><<<4*1344,256,0,stream>>>(y,   802816, l10Wih, l10b, l20Wih, l20b, pre);
  lstm_kernel<<<128,64,0,stream>>>(pre, l10Whh, l20Whh, ol0);
  pregate_kernel<24><<<4*1344,256,0,stream>>>(ol0, 688128, l11Wih, l11b, l21Wih, l21b, pre);
  lstm_kernel<<<128,64,0,stream>>>(pre, l11Whh, l21Whh, ol1);
  wcomp1_kernel<<<36,256,0,stream>>>(fcw3, fcw2, Wt);
  wpartA_kernel<<<336,256,0,stream>>>(Wt, fcw1, wpart);
  wpartB_kernel<<<189,256,0,stream>>>(wpart, Wc);
  bcomp_kernel<<<9,64,0,stream>>>(Wt, fcb1, fcb2, fcw3, fcb3, BC);
  final_kernel<<<288,256,0,stream>>>(ol1, ol1+688128, Wc, BC, w1, w2, out);
}

// Round 7
// 195.118 us; speedup vs baseline: 2.8439x; 1.0570x over previous
//
#include <hip/hip_runtime.h>

#define BB 128
#define TT 224
#define LL 224

typedef float v2f __attribute__((ext_vector_type(2)));

__device__ __forceinline__ float rcpf(float x){ return __builtin_amdgcn_rcpf(x); }

#if __has_builtin(__builtin_amdgcn_exp2f)
#define EXP2(x) __builtin_amdgcn_exp2f(x)
#else
#define EXP2(x) __expf((x)*0.6931471805599453f)
#endif

// DPP row rotate-right by N: dst[k] = src[(k-N)&15] within each 16-lane row
template<int N>
__device__ __forceinline__ float rorN(float x){
  int xi = __builtin_bit_cast(int, x);
  xi = __builtin_amdgcn_update_dpp(xi, xi, 0x120 + N, 0xf, 0xf, false);
  return __builtin_bit_cast(float, xi);
}

// ds_swizzle xor-16: partner row within each 32-lane half (BitMode 0x401F)
__device__ __forceinline__ float swz16(float x){
  int xi = __builtin_bit_cast(int, x);
  xi = __builtin_amdgcn_ds_swizzle(xi, 0x401F);
  return __builtin_bit_cast(float, xi);
}

// ---------------- K1: conv chain, LDS-staged (both branches) ----------------
__global__ __launch_bounds__(256) void conv_chain_kernel(const float* __restrict__ x,
    const float* __restrict__ c1w1, const float* __restrict__ c1b1,
    const float* __restrict__ c1w2, const float* __restrict__ c1b2,
    const float* __restrict__ c2w1, const float* __restrict__ c2b1,
    const float* __restrict__ c2w2, const float* __restrict__ c2b2,
    float* __restrict__ y)
{
  __shared__ float xs[4*224];
  __shared__ float c1s[4*56];
  int gid = blockIdx.x;
  int tid = threadIdx.x;
  int branch = (gid >= 7168);
  const float* w1 = branch ? c2w1 : c1w1;
  const float* w2 = branch ? c2w2 : c1w2;
  float b1  = branch ? c2b1[0] : c1b1[0];
  float b2v = branch ? c2b2[0] : c1b2[0];

  if (tid < 224){
    *(float4*)&xs[tid*4] = *((const float4*)x + (size_t)gid*224 + tid);
  }
  __syncthreads();
  if (tid < 224){
    int rr = tid / 56, cj = tid - rr*56;
    int base = 4*cj - 2;
    const float* xr = &xs[rr*224];
    float s = b1;
    #pragma unroll
    for (int kk=0;kk<8;kk++){
      int xi = base + kk;
      float xv = (xi>=0 && xi<224) ? xr[xi] : 0.f;
      s += xv * w1[kk];
    }
    c1s[rr*56 + cj] = fmaxf(s, 0.f);
  }
  __syncthreads();
  if (tid < 112){
    int rr = tid / 28, j = tid - rr*28;
    const float* cr = &c1s[rr*56];
    float o = b2v;
    #pragma unroll
    for (int pi=0;pi<3;pi++){
      int p = j - 1 + pi;
      float pool = 0.f;
      if (p>=0 && p<28){
        int i0 = 2*p - 1;
        float m = -1e30f;
        #pragma unroll
        for (int q=0;q<4;q++){
          int ii = i0+q;
          if (ii>=0 && ii<56) m = fmaxf(m, cr[ii]);
        }
        pool = fmaxf(m, 0.f);
      }
      o += pool * w2[pi];
    }
    y[(size_t)gid*112 + tid] = fmaxf(o, 0.f);
  }
}

// ---------------- K2: pre-gate GEMM (templated D, fully unrolled) ----------
template<int D>
__global__ void pregate_kernel(const float* __restrict__ in, int inStrideBranch,
    const float* __restrict__ wihA, const float* __restrict__ biasA,
    const float* __restrict__ wihB, const float* __restrict__ biasB,
    float* __restrict__ pre)
{
  int r = blockIdx.x / 1344;
  int lin = (blockIdx.x % 1344)*256 + threadIdx.x;
  int br = r>>1, dir = r&1;
  const float* wih  = (br ? wihB  : wihA)  + dir*48*D;
  const float* bias = (br ? biasB : biasA) + dir*48;
  __shared__ float wL[48*D];
  __shared__ float bL[48];
  for (int i = threadIdx.x; i < 48*D; i += 256) wL[i]=wih[i];
  if (threadIdx.x < 48) bL[threadIdx.x]=bias[threadIdx.x];
  __syncthreads();
  int tb = lin/12;  int k = lin - tb*12;
  int t  = tb >> 7; int b = tb & 127;
  const float* rowp = in + (size_t)br*inStrideBranch + ((size_t)b*TT + t)*D;
  float aI=bL[k], aF=bL[12+k], aG=bL[24+k], aO=bL[36+k];
  const float4* rp4 = (const float4*)rowp;
  #pragma unroll
  for (int d4=0; d4<D/4; d4++){
    float4 xv = rp4[d4];
    float4 wI = *(const float4*)&wL[(0*12+k)*D + d4*4];
    float4 wF = *(const float4*)&wL[(1*12+k)*D + d4*4];
    float4 wG = *(const float4*)&wL[(2*12+k)*D + d4*4];
    float4 wO = *(const float4*)&wL[(3*12+k)*D + d4*4];
    aI += xv.x*wI.x + xv.y*wI.y + xv.z*wI.z + xv.w*wI.w;
    aF += xv.x*wF.x + xv.y*wF.y + xv.z*wF.z + xv.w*wF.w;
    aG += xv.x*wG.x + xv.y*wG.y + xv.z*wG.z + xv.w*wG.w;
    aO += xv.x*wO.x + xv.y*wO.y + xv.z*wO.z + xv.w*wO.w;
  }
  float4* o = (float4*)(pre + (size_t)r*(TT*BB*48) + (size_t)tb*48 + k*4);
  *o = make_float4(aI,aF,aG,aO);
}

// ---------------- K3: recurrent LSTM scan, gate-distributed --------------
// 64 lanes = 2 batches x 2 rows x 16 units. Row 0 of each 32-half holds
// gates (i,f) packed v2f; row 1 holds (g,o). Per step: 15 shared DPP taps +
// 16 pk-FMA; ONE exp/rcp pair (x2 packed halves) covers every gate of both
// batches; ds_swizzle xor16 exchanges nonlinear results between rows; both
// rows then redundantly compute c,h so h is already in place for next
// step's row-local DPP rotation (no broadcast). 256 blocks, 1 wave each.
#define LSTM_STEP(P, SS) { \
  float x1=rorN<1>(hv), x2=rorN<2>(hv), x3=rorN<3>(hv), x4=rorN<4>(hv), \
        x5=rorN<5>(hv), x6=rorN<6>(hv), x7=rorN<7>(hv), x8=rorN<8>(hv), \
        x9=rorN<9>(hv), x10=rorN<10>(hv), x11=rorN<11>(hv), x12=rorN<12>(hv), \
        x13=rorN<13>(hv), x14=rorN<14>(hv), x15=rorN<15>(hv); \
  v2f a0 = (P); \
  a0 += w[0]*(v2f){hv,hv};   a0 += w[1]*(v2f){x1,x1};   a0 += w[2]*(v2f){x2,x2};   a0 += w[3]*(v2f){x3,x3}; \
  v2f a1 = w[4]*(v2f){x4,x4};   a1 += w[5]*(v2f){x5,x5};   a1 += w[6]*(v2f){x6,x6};   a1 += w[7]*(v2f){x7,x7}; \
  v2f a2 = w[8]*(v2f){x8,x8};   a2 += w[9]*(v2f){x9,x9};   a2 += w[10]*(v2f){x10,x10}; a2 += w[11]*(v2f){x11,x11}; \
  v2f a3 = w[12]*(v2f){x12,x12}; a3 += w[13]*(v2f){x13,x13}; a3 += w[14]*(v2f){x14,x14}; a3 += w[15]*(v2f){x15,x15}; \
  v2f gg = (a0+a1)+(a2+a3); \
  v2f m  = gg*kmul; \
  v2f e  = { EXP2(m.x), EXP2(m.y) }; \
  e += (v2f){1.f,1.f}; \
  v2f d  = { rcpf(e.x), rcpf(e.y) }; \
  v2f res = ca*d + cb; \
  float px = swz16(res.x); \
  float py = swz16(res.y); \
  float sf_ = rbit ? py : res.y; \
  float so_ = rbit ? res.y : py; \
  cst = fmaf(sf_, cst, res.x*px); \
  float et = EXP2(cst*2.885390082f); \
  float dt = rcpf(et+1.f); \
  hv = so_*fmaf(-2.f, dt, 1.f); \
  hbuf[SS] = hv; }

#define FLUSH8 { \
  if (doSt){ \
    _Pragma("unroll") \
    for (int q=0;q<8;q++) outP[q*ostep] = hbuf[q]; \
  } \
  outP += 8*ostep; }

__global__ __launch_bounds__(64) __attribute__((amdgpu_waves_per_eu(1,1)))
void lstm_kernel(const float* __restrict__ pre,
    const float* __restrict__ whhA, const float* __restrict__ whhB,
    float* __restrict__ out)
{
  int blk  = blockIdx.x;
  int r    = blk >> 6;           // run 0..3 (64 blocks per run)
  int br   = r >> 1, dir = r & 1;
  int lane = threadIdx.x;
  int u    = lane & 15;          // hidden unit
  int rbit = (lane >> 4) & 1;    // 0: (i,f) row, 1: (g,o) row
  int bh   = lane >> 5;          // batch half
  int b    = (blk & 63)*2 + bh;
  const float* whh = (br ? whhB : whhA) + dir*48*12;

  // packed rotation-ordered weights: at rotation rr, lane holds h_{(u-rr)&15}
  v2f w[16];
  #pragma unroll
  for (int rr=0; rr<16; rr++){
    int j = (u - rr) & 15;
    bool vld = (j < 12) && (u < 12);
    int uw = (u < 12) ? u : 0;
    int jw = (j < 12) ? j : 0;
    float wa = whh[((rbit?24:0)  + uw)*12 + jw];   // g : i
    float wb = whh[((rbit?36:12) + uw)*12 + jw];   // o : f
    w[rr] = (v2f){ vld ? wa : 0.f, vld ? wb : 0.f };
  }
  // sigma(x)=rcp(1+2^(-1.4427x)); tanh(x)=1-2*rcp(1+2^(2.8854x))
  const v2f kmul = rbit ? (v2f){2.885390082f, -1.442695041f}
                        : (v2f){-1.442695041f, -1.442695041f};
  const v2f ca   = rbit ? (v2f){-2.f, 1.f} : (v2f){1.f, 1.f};
  const v2f cb   = rbit ? (v2f){ 1.f, 0.f} : (v2f){0.f, 0.f};

  const float* preR = pre + (size_t)r*(TT*BB*48) + b*48 + u*4 + rbit*2;
  const int sstep = dir ? -6144 : 6144;   // float stride per t
  int scb = dir ? 223*6144 : 0;

  v2f pcur[8], pnext[8];
  #pragma unroll
  for (int i=0;i<8;i++) pcur[i]  = *(const v2f*)(preR + scb +  i   *sstep);
  #pragma unroll
  for (int i=0;i<8;i++) pnext[i] = *(const v2f*)(preR + scb + (i+8)*sstep);
  int lb = scb + 16*sstep;

  float hv = 0.f, cst = 0.f;
  float hbuf[8];
  const int ostep = dir ? -24 : 24;
  float* outP = out + (size_t)br*(BB*TT*24) + (size_t)b*TT*24 + dir*12 + u
              + (size_t)(dir ? 223 : 0)*24;
  const bool doSt = (rbit==0) && (u < 12);

  for (int c=0;c<14;c++){
    LSTM_STEP(pcur[0],0) LSTM_STEP(pcur[1],1) LSTM_STEP(pcur[2],2) LSTM_STEP(pcur[3],3)
    LSTM_STEP(pcur[4],4) LSTM_STEP(pcur[5],5) LSTM_STEP(pcur[6],6) LSTM_STEP(pcur[7],7)
    FLUSH8
    if (c < 13){
      #pragma unroll
      for (int i=0;i<8;i++) pcur[i] = *(const v2f*)(preR + lb + i*sstep);
      lb += 8*sstep;
    }
    LSTM_STEP(pnext[0],0) LSTM_STEP(pnext[1],1) LSTM_STEP(pnext[2],2) LSTM_STEP(pnext[3],3)
    LSTM_STEP(pnext[4],4) LSTM_STEP(pnext[5],5) LSTM_STEP(pnext[6],6) LSTM_STEP(pnext[7],7)
    FLUSH8
    if (c < 13){
      #pragma unroll
      for (int i=0;i<8;i++) pnext[i] = *(const v2f*)(preR + lb + i*sstep);
      lb += 8*sstep;
    }
  }
}

// ---------------- K6a: Wt = W3(9,192) @ W2(192,1024) ----------------------
__global__ void wcomp1_kernel(const float* __restrict__ fcw3, const float* __restrict__ fcw2,
                              float* __restrict__ Wt)
{
  int idx = blockIdx.x*256+threadIdx.x;
  if (idx >= 9*1024) return;
  int o = idx >> 10;
  int n = idx & 1023;
  float acc = 0.f;
  for (int p=0;p<192;p++) acc += fcw3[o*192+p]*fcw2[p*1024+n];
  Wt[idx] = acc;
}

// ---------------- K6b-A: split-K partials  wpart[s][o][j] ------------------
__global__ void wpartA_kernel(const float* __restrict__ Wt, const float* __restrict__ fcw1,
                              float* __restrict__ wpart)
{
  int s  = blockIdx.x / 21;
  int jb = blockIdx.x % 21;
  int j  = jb*256 + threadIdx.x;      // < 5376
  __shared__ float wtL[9*64];
  for (int i=threadIdx.x;i<9*64;i+=256){
    int o=i>>6, n=i&63;
    wtL[i]=Wt[o*1024 + s*64 + n];
  }
  __syncthreads();
  float acc[9];
  #pragma unroll
  for (int o=0;o<9;o++) acc[o]=0.f;
  int nbase = s*64;
  for (int n=0;n<64;n++){
    float v = fcw1[(size_t)(nbase+n)*5376 + j];
    #pragma unroll
    for (int o=0;o<9;o++) acc[o] += wtL[o*64+n]*v;
  }
  #pragma unroll
  for (int o=0;o<9;o++) wpart[((size_t)s*9+o)*5376 + j] = acc[o];
}

// ---------------- K6b-B: Wc = sum_s wpart[s] ------------------------------
__global__ void wpartB_kernel(const float* __restrict__ wpart, float* __restrict__ Wc)
{
  int idx = blockIdx.x*256+threadIdx.x;     // 189 blocks = 48384
  if (idx >= 48384) return;
  float a = 0.f;
  #pragma unroll
  for (int s=0;s<16;s++) a += wpart[(size_t)s*48384 + idx];
  Wc[idx] = a;
}

// ---------------- K6b-C: composite bias BC --------------------------------
__global__ void bcomp_kernel(const float* __restrict__ Wt,
    const float* __restrict__ fcb1, const float* __restrict__ fcb2,
    const float* __restrict__ fcw3, const float* __restrict__ fcb3,
    float* __restrict__ BC)
{
  int o = blockIdx.x;           // 9 blocks, 64 threads
  int lane = threadIdx.x;
  float acc = 0.f;
  for (int p=lane;p<192;p+=64)  acc += fcw3[o*192+p]*fcb2[p];
  for (int n=lane;n<1024;n+=64) acc += Wt[o*1024+n]*fcb1[n];
  #pragma unroll
  for (int off=32;off;off>>=1) acc += __shfl_down(acc, off);
  if (lane==0) BC[o] = acc + fcb3[o];
}

// ---------------- K6c: out[m][o] = (w1*o1+w2*o2) . Wc[o] + BC[o] ----------
__global__ void final_kernel(const float* __restrict__ o1, const float* __restrict__ o2,
    const float* __restrict__ Wc, const float* __restrict__ BC,
    const float* __restrict__ w1p, const float* __restrict__ w2p,
    float* __restrict__ out)
{
  int wid  = blockIdx.x*4 + (threadIdx.x>>6);
  int lane = threadIdx.x & 63;
  if (wid >= 128*9) return;
  int m = wid / 9, o = wid - m*9;
  float w1 = w1p[0], w2 = w2p[0];
  const float* r1 = o1 + (size_t)m*5376;
  const float* r2 = o2 + (size_t)m*5376;
  const float* wc = Wc + (size_t)o*5376;
  float acc = 0.f;
  for (int i=lane;i<5376;i+=64){
    acc += (w1*r1[i] + w2*r2[i]) * wc[i];
  }
  #pragma unroll
  for (int off=32;off;off>>=1) acc += __shfl_down(acc, off);
  if (lane==0) out[m*9+o] = acc + BC[o];
}

extern "C" void kernel_launch(void* const* d_in, const int* in_sizes, int n_in,
                              void* d_out, int out_size, void* d_ws, size_t ws_size,
                              hipStream_t stream) {
  (void)in_sizes; (void)n_in; (void)out_size; (void)ws_size;
  const float* x    = (const float*)d_in[0];
  const float* c1w1 = (const float*)d_in[1];
  const float* c1b1 = (const float*)d_in[2];
  const float* c1w2 = (const float*)d_in[3];
  const float* c1b2 = (const float*)d_in[4];
  const float* c2w1 = (const float*)d_in[5];
  const float* c2b1 = (const float*)d_in[6];
  const float* c2w2 = (const float*)d_in[7];
  const float* c2b2 = (const float*)d_in[8];
  const float* l10Wih = (const float*)d_in[9];
  const float* l10Whh = (const float*)d_in[10];
  const float* l10b   = (const float*)d_in[11];
  const float* l11Wih = (const float*)d_in[12];
  const float* l11Whh = (const float*)d_in[13];
  const float* l11b   = (const float*)d_in[14];
  const float* l20Wih = (const float*)d_in[15];
  const float* l20Whh = (const float*)d_in[16];
  const float* l20b   = (const float*)d_in[17];
  const float* l21Wih = (const float*)d_in[18];
  const float* l21Whh = (const float*)d_in[19];
  const float* l21b   = (const float*)d_in[20];
  const float* fcw1 = (const float*)d_in[21];
  const float* fcb1 = (const float*)d_in[22];
  const float* fcw2 = (const float*)d_in[23];
  const float* fcb2 = (const float*)d_in[24];
  const float* fcw3 = (const float*)d_in[25];
  const float* fcb3 = (const float*)d_in[26];
  const float* w1   = (const float*)d_in[27];
  const float* w2   = (const float*)d_in[28];
  float* out = (float*)d_out;

  float* ws  = (float*)d_ws;
  float* y    = ws;                       // 2 * 802816  (dead after pregate #1)
  float* pre  = y   + 2*802816;           // 4 * 1376256
  float* ol0  = pre + 4*1376256;          // 2 * 688128
  float* ol1  = ol0 + 2*688128;           // 2 * 688128
  float* Wt   = ol1 + 2*688128;           // 9216
  float* Wc   = Wt  + 9216;               // 48384
  float* BC   = Wc  + 48384;              // 9
  float* wpart = y;                       // alias: 16*9*5376 = 774144 < 1605632

  conv_chain_kernel<<<14336,256,0,stream>>>(x, c1w1,c1b1,c1w2,c1b2, c2w1,c2b1,c2w2,c2b2, y);
  pregate_kernel<28><<<4*1344,256,0,stream>>>(y,   802816, l10Wih, l10b, l20Wih, l20b, pre);
  lstm_kernel<<<256,64,0,stream>>>(pre, l10Whh, l20Whh, ol0);
  pregate_kernel<24><<<4*1344,256,0,stream>>>(ol0, 688128, l11Wih, l11b, l21Wih, l21b, pre);
  lstm_kernel<<<256,64,0,stream>>>(pre, l11Whh, l21Whh, ol1);
  wcomp1_kernel<<<36,256,0,stream>>>(fcw3, fcw2, Wt);
  wpartA_kernel<<<336,256,0,stream>>>(Wt, fcw1, wpart);
  wpartB_kernel<<<189,256,0,stream>>>(wpart, Wc);
  bcomp_kernel<<<9,64,0,stream>>>(Wt, fcb1, fcb2, fcw3, fcb3, BC);
  final_kernel<<<288,256,0,stream>>>(ol1, ol1+688128, Wc, BC, w1, w2, out);
}